// Round 14
// baseline (519.491 us; speedup 1.0000x reference)
//
#include <hip/hip_runtime.h>
#include <hip/hip_fp16.h>
#include <math.h>

#define IN_DIM 128
#define HD 256
#define EPSLN 1e-5f

typedef _Float16 half8 __attribute__((ext_vector_type(8)));
typedef float f32x4 __attribute__((ext_vector_type(4)));
typedef float f32x2 __attribute__((ext_vector_type(2)));

// ---------------- helpers ----------------
__device__ inline void store4(float* p, float4 o) { *(float4*)p = o; }
__device__ inline void store4(__half* p, float4 o) {
    union { uint2 u; __half2 h[2]; } s;
    s.h[0] = __floats2half2_rn(o.x, o.y);
    s.h[1] = __floats2half2_rn(o.z, o.w);
    *(uint2*)p = s.u;
}
__device__ inline float4 h4_to_f4(uint2 u) {
    union { unsigned int w; __half2 h; } a, b;
    a.w = u.x; b.w = u.y;
    float2 lo = __half22float2(a.h), hi = __half22float2(b.h);
    return make_float4(lo.x, lo.y, hi.x, hi.y);
}
// 4 floats -> 4 packed fp8 e4m3 (OCP, gfx950 HW cvt)
__device__ inline unsigned int f4_to_fp8x4(float a, float b, float c, float d) {
    int v = 0;
    v = __builtin_amdgcn_cvt_pk_fp8_f32(a, b, v, false);
    v = __builtin_amdgcn_cvt_pk_fp8_f32(c, d, v, true);
    return (unsigned int)v;
}
__device__ inline float4 fp8x4_to_f4(unsigned int u) {
    f32x2 lo = __builtin_amdgcn_cvt_pk_f32_fp8((int)u, false);
    f32x2 hi = __builtin_amdgcn_cvt_pk_f32_fp8((int)u, true);
    return make_float4(lo.x, lo.y, hi.x, hi.y);
}

__device__ inline void async_copy16(const __half* g, _Float16* l) {
    __builtin_amdgcn_global_load_lds(
        (const __attribute__((address_space(1))) void*)g,
        (__attribute__((address_space(3))) void*)l,
        16, 0, 0);
}

// Packed output column mapping: q[0:256) | kv-interleaved[256:768) | skip[768:1024)
__device__ inline void unpermute_col(int n, int& sel, int& c) {
    if (n < 256) { sel = 0; c = n; }
    else if (n < 768) {
        int j = n - 256, chunk = j >> 3, w = j & 7;
        if (w < 4) { sel = 1; c = chunk * 4 + w; }
        else       { sel = 2; c = chunk * 4 + w - 4; }
    } else { sel = 3; c = n - 768; }
}

// ---------------- fused prep: pack x, pack weights/biases, count degrees ----
// R20: counts atomic is now FIRE-AND-FORGET (no return value -> no per-wave
// dependency chain); the per-edge slot claim moved to scatter_k's cursor
// atomic. rank array deleted entirely (-6.4MB round-trip traffic).
__global__ void prep_k(
    const float4* __restrict__ x, __half* __restrict__ xh, int total4,
    const int* __restrict__ dst, int* __restrict__ counts, int E,
    const float* __restrict__ Wq1, const float* __restrict__ Wk1,
    const float* __restrict__ Wv1, const float* __restrict__ Ws1,
    const float* __restrict__ Wq2, const float* __restrict__ Wk2,
    const float* __restrict__ Wv2, const float* __restrict__ Ws2,
    const float* __restrict__ Wo,
    const float* __restrict__ bq1, const float* __restrict__ bk1,
    const float* __restrict__ bv1, const float* __restrict__ bs1,
    const float* __restrict__ bq2, const float* __restrict__ bk2,
    const float* __restrict__ bv2, const float* __restrict__ bs2,
    __half* __restrict__ Wc1, __half* __restrict__ Wc2, __half* __restrict__ Wot,
    float* __restrict__ bc1, float* __restrict__ bc2)
{
    int idx = blockIdx.x * 256 + threadIdx.x;
    if (idx < total4) store4(xh + (size_t)idx * 4, x[idx]);
    if (idx < E) atomicAdd(&counts[dst[idx]], 1);   // histogram only, no return
    if (idx < 131072) {
        int n = idx >> 7, k = idx & 127;
        int sel, c; unpermute_col(n, sel, c);
        const float* W = (sel == 0) ? Wq1 : (sel == 1) ? Wk1 : (sel == 2) ? Wv1 : Ws1;
        Wc1[idx] = __float2half(W[(size_t)k * 256 + c]);
    } else if (idx < 393216) {
        int j = idx - 131072;
        int n = j >> 8, k = j & 255;
        int sel, c; unpermute_col(n, sel, c);
        const float* W = (sel == 0) ? Wq2 : (sel == 1) ? Wk2 : (sel == 2) ? Wv2 : Ws2;
        Wc2[j] = __float2half(W[(size_t)k * 256 + c]);
    } else if (idx < 409600) {
        int j = idx - 393216;
        int n = j >> 8, k = j & 255;
        Wot[j] = __float2half(Wo[(size_t)k * 64 + n]);
    } else if (idx < 410624) {
        int n = idx - 409600;
        int sel, c; unpermute_col(n, sel, c);
        const float* b = (sel == 0) ? bq1 : (sel == 1) ? bk1 : (sel == 2) ? bv1 : bs1;
        bc1[n] = b[c];
    } else if (idx < 411648) {
        int n = idx - 410624;
        int sel, c; unpermute_col(n, sel, c);
        const float* b = (sel == 0) ? bq2 : (sel == 1) ? bk2 : (sel == 2) ? bv2 : bs2;
        bc2[n] = b[c];
    }
}

// ---------------- MFMA GEMM: C[M x Nc] = A[M x K] @ Wt^T + bias (f16 out) ----------------
// R13: 1-D grid + XCD-grouping swizzle (measured R4: ~44us win across both gemms).
// R17/R18: BK=32 single-barrier double-buffer (measured R11: neutral; kept as
// the verified config). LDS: As0@0, Bs0@8K, As1@16K, Bs1@24K within the
// 34,816B epilogue region. Buffer bases computed per-use (LDS pointer arrays
// fail to compile on gfx950 — R10 lesson).
#define BM 128
#define BN 128
#define TROWB 272   // f16 out-tile row stride (bytes)

__global__ __launch_bounds__(256) void gemm_mfma(
    const __half* __restrict__ A, const __half* __restrict__ Wt,
    const float* __restrict__ bias, __half* __restrict__ C,
    unsigned char* __restrict__ kv8,
    int M, int K, int Nc)
{
    __shared__ char smem[BM * TROWB];          // 34,816 B; dbuf overlaid below

    int tid = threadIdx.x;
    int lane = tid & 63, w = tid >> 6;
    int wm = w >> 1, wn = w & 1;
    int quad = lane >> 4, l16 = lane & 15;
    // XCD swizzle: nwg = nbx*8 (exact multiple of 8 XCDs)
    int nbx = (int)gridDim.x >> 3;
    int wkr = ((int)blockIdx.x & 7) * nbx + ((int)blockIdx.x >> 3);
    int row0 = (wkr >> 3) * BM;
    int col0 = (wkr & 7) * BN;

    f32x4 acc[4][4];
#pragma unroll
    for (int i = 0; i < 4; i++)
#pragma unroll
        for (int j = 0; j < 4; j++) acc[i][j] = (f32x4){0.f, 0.f, 0.f, 0.f};

    int srow = lane >> 2;      // 0..15 (16 rows per wave-instruction at BK=32)
    int schunk = lane & 3;     // 4 chunks of 8 f16 per 64B row

    int nt = K >> 5;           // K/32 steps

    // STAGE(step, buf): issue A+B tile loads for k0 = step*32 into buffer buf
    auto STAGE = [&](int step, int buf) {
        int k0 = step << 5;
        _Float16* Asb = (_Float16*)(smem + buf * 16384);
        _Float16* Bsb = (_Float16*)(smem + 8192 + buf * 16384);
#pragma unroll
        for (int t = 0; t < 2; t++) {
            int r = w * 32 + t * 16 + srow;
            int gr = row0 + r; if (gr > M - 1) gr = M - 1;
            int gchunk = schunk ^ ((r ^ (r >> 2)) & 3);
            async_copy16(&A[(size_t)gr * K + k0 + gchunk * 8], &Asb[(w * 32 + t * 16) * 32]);
        }
#pragma unroll
        for (int t = 0; t < 2; t++) {
            int r = w * 32 + t * 16 + srow;
            int gc = col0 + r; if (gc > Nc - 1) gc = Nc - 1;
            int gchunk = schunk ^ ((r ^ (r >> 2)) & 3);
            async_copy16(&Wt[(size_t)gc * K + k0 + gchunk * 8], &Bsb[(w * 32 + t * 16) * 32]);
        }
    };

    STAGE(0, 0);
    __syncthreads();

    for (int t = 0; t < nt; ++t) {
        if (t + 1 < nt) STAGE(t + 1, (t + 1) & 1);
        _Float16* Asb = (_Float16*)(smem + (t & 1) * 16384);
        _Float16* Bsb = (_Float16*)(smem + 8192 + (t & 1) * 16384);
        half8 af[4], bf[4];
#pragma unroll
        for (int i = 0; i < 4; i++) {
            int ra = wm * 64 + i * 16 + l16;
            af[i] = *(half8*)&Asb[ra * 32 + ((quad ^ ((ra ^ (ra >> 2)) & 3)) * 8)];
            int rb = wn * 64 + i * 16 + l16;
            bf[i] = *(half8*)&Bsb[rb * 32 + ((quad ^ ((rb ^ (rb >> 2)) & 3)) * 8)];
        }
#pragma unroll
        for (int i = 0; i < 4; i++)
#pragma unroll
            for (int j = 0; j < 4; j++)
                acc[i][j] = __builtin_amdgcn_mfma_f32_16x16x32_f16(af[i], bf[j], acc[i][j], 0, 0, 0);
        __syncthreads();
    }

#pragma unroll
    for (int j = 0; j < 4; j++) {
        int tcol = wn * 64 + j * 16 + l16;
        float bb = (col0 + tcol < Nc) ? bias[col0 + tcol] : 0.f;
#pragma unroll
        for (int i = 0; i < 4; i++) {
#pragma unroll
            for (int r = 0; r < 4; r++) {
                int trow = wm * 64 + i * 16 + quad * 4 + r;
                ((__half*)(smem + trow * TROWB))[tcol] = __float2half(acc[i][j][r] + bb);
            }
        }
    }
    __syncthreads();
    bool iskv = (col0 >= 256) && (col0 < 768);
    int crow = tid >> 4, cchunk = tid & 15;
    for (int p = 0; p < 8; p++) {
        int trow = p * 16 + crow;
        int grow = row0 + trow;
        if (grow >= M) continue;
        uint4 val = *(uint4*)(smem + trow * TROWB + cchunk * 16);
        if (iskv) {
            float4 lo = h4_to_f4(make_uint2(val.x, val.y));
            float4 hi = h4_to_f4(make_uint2(val.z, val.w));
            uint2 o8;
            o8.x = f4_to_fp8x4(lo.x, lo.y, lo.z, lo.w);
            o8.y = f4_to_fp8x4(hi.x, hi.y, hi.z, hi.w);
            *(uint2*)&kv8[(size_t)grow * 512 + (col0 - 256) + cchunk * 8] = o8;
        } else {
            *(uint4*)&C[(size_t)grow * Nc + col0 + cchunk * 8] = val;
        }
    }
}

// ---------------- output GEMM: D[M x 64] = A[M x 256] @ Wot^T + bo (fp32 out) ----------
// R17/R18: BK=32 single-barrier double-buffer. LDS 24KB.
// Layout (halfs): As0@0 (4096), As1@4096, Bs0@8192 (2048), Bs1@10240.
__global__ __launch_bounds__(256) void gemm_out_k(
    const __half* __restrict__ A, const __half* __restrict__ Wot,
    const float* __restrict__ bias, float* __restrict__ D, int M)
{
    __shared__ _Float16 smem[12288];   // 24 KB
    int tid = threadIdx.x;
    int lane = tid & 63, w = tid >> 6;
    int quad = lane >> 4, l16 = lane & 15;
    int row0 = blockIdx.x * 128;
    const int K = 256;

    f32x4 acc[2][4];
#pragma unroll
    for (int i = 0; i < 2; i++)
#pragma unroll
        for (int j = 0; j < 4; j++) acc[i][j] = (f32x4){0.f, 0.f, 0.f, 0.f};

    int srow = lane >> 2;
    int schunk = lane & 3;
    const int nt = 8;   // 256/32

    auto STAGE = [&](int step, int buf) {
        int k0 = step << 5;
        _Float16* Asb = smem + buf * 4096;
        _Float16* Bsb = smem + 8192 + buf * 2048;
#pragma unroll
        for (int t = 0; t < 2; t++) {
            int r = w * 32 + t * 16 + srow;
            int gr = row0 + r; if (gr > M - 1) gr = M - 1;
            int gchunk = schunk ^ ((r ^ (r >> 2)) & 3);
            async_copy16(&A[(size_t)gr * K + k0 + gchunk * 8], &Asb[(w * 32 + t * 16) * 32]);
        }
        {
            int r = w * 16 + srow;       // 64 weight rows, one wave-inst per wave
            int gchunk = schunk ^ ((r ^ (r >> 2)) & 3);
            async_copy16(&Wot[(size_t)r * K + k0 + gchunk * 8], &Bsb[(w * 16) * 32]);
        }
    };

    STAGE(0, 0);
    __syncthreads();

    for (int t = 0; t < nt; ++t) {
        if (t + 1 < nt) STAGE(t + 1, (t + 1) & 1);
        _Float16* Asb = smem + (t & 1) * 4096;
        _Float16* Bsb = smem + 8192 + (t & 1) * 2048;
        half8 af[2], bf[4];
#pragma unroll
        for (int i = 0; i < 2; i++) {
            int ra = w * 32 + i * 16 + l16;
            af[i] = *(half8*)&Asb[ra * 32 + ((quad ^ ((ra ^ (ra >> 2)) & 3)) * 8)];
        }
#pragma unroll
        for (int j = 0; j < 4; j++) {
            int rb = j * 16 + l16;
            bf[j] = *(half8*)&Bsb[rb * 32 + ((quad ^ ((rb ^ (rb >> 2)) & 3)) * 8)];
        }
#pragma unroll
        for (int i = 0; i < 2; i++)
#pragma unroll
            for (int j = 0; j < 4; j++)
                acc[i][j] = __builtin_amdgcn_mfma_f32_16x16x32_f16(af[i], bf[j], acc[i][j], 0, 0, 0);
        __syncthreads();
    }

#pragma unroll
    for (int i = 0; i < 2; i++) {
#pragma unroll
        for (int j = 0; j < 4; j++) {
            int gcol = j * 16 + l16;
            float bb = bias[gcol];
#pragma unroll
            for (int r = 0; r < 4; r++) {
                int grow = row0 + w * 32 + i * 16 + quad * 4 + r;
                if (grow < M) D[(size_t)grow * 64 + gcol] = acc[i][j][r] + bb;
            }
        }
    }
}

// ---------------- edge bucketing: 3-phase parallel scan (R19, measured -87us w/ ln fix) ----
__global__ __launch_bounds__(256) void scan_part_k(const int* __restrict__ counts,
                                                   int* __restrict__ part, int n)
{
    int b = blockIdx.x, t = threadIdx.x;
    int i0 = b * 512 + t * 2;
    int s = 0;
    if (i0 < n) s += counts[i0];
    if (i0 + 1 < n) s += counts[i0 + 1];
    int lane = t & 63, wid = t >> 6;
    int v = s;
#pragma unroll
    for (int d = 1; d < 64; d <<= 1) v += __shfl_xor(v, d);
    __shared__ int ws[4];
    if (lane == 0) ws[wid] = v;
    __syncthreads();
    if (t == 0) part[b] = ws[0] + ws[1] + ws[2] + ws[3];
}

__global__ __launch_bounds__(128) void scan_top_k(int* __restrict__ part, int nb)
{
    // exclusive prefix over nb (<=128) entries, in place
    int t = threadIdx.x, lane = t & 63, wid = t >> 6;
    int orig = (t < nb) ? part[t] : 0;
    int v = orig;
#pragma unroll
    for (int d = 1; d < 64; d <<= 1) {
        int u = __shfl_up(v, (unsigned)d, 64);
        if (lane >= d) v += u;
    }
    __shared__ int wsum[2];
    if (lane == 63) wsum[wid] = v;
    __syncthreads();
    int add = (wid == 1) ? wsum[0] : 0;
    if (t < nb) part[t] = v + add - orig;   // exclusive base
}

// R20: also emits cursor[] (a second copy of the exclusive prefix) for
// scatter_k's slot-claim atomics.
__global__ __launch_bounds__(256) void scan_fix_k(const int* __restrict__ counts,
                                                  const int* __restrict__ part,
                                                  int* __restrict__ offs,
                                                  int* __restrict__ cursor, int n)
{
    int b = blockIdx.x, t = threadIdx.x;
    int lane = t & 63, wid = t >> 6;
    int i0 = b * 512 + t * 2;
    int c0 = (i0 < n) ? counts[i0] : 0;
    int c1 = (i0 + 1 < n) ? counts[i0 + 1] : 0;
    int s = c0 + c1;
    int v = s;
#pragma unroll
    for (int d = 1; d < 64; d <<= 1) {
        int u = __shfl_up(v, (unsigned)d, 64);
        if (lane >= d) v += u;
    }
    __shared__ int wsum[4], wpre[4];
    if (lane == 63) wsum[wid] = v;
    __syncthreads();
    if (t == 0) { int a = 0; for (int i = 0; i < 4; i++) { wpre[i] = a; a += wsum[i]; } }
    __syncthreads();
    int pre = part[b] + wpre[wid] + v - s;   // exclusive prefix for this thread
    if (i0 < n) { offs[i0] = pre; cursor[i0] = pre; }
    if (i0 + 1 < n) { offs[i0 + 1] = pre + c0; cursor[i0 + 1] = pre + c0; }
    int end = i0 + 2; if (end > n) end = n;
    if (end == n) offs[n] = pre + c0 + c1;   // racing writers all write the total
}

// R20: slot claim via cursor atomic (replaces prep's returning atomic + rank
// array + scatter's random offs[dst] gather). Bucket order is arbitrary;
// attn's online softmax is order-independent within tolerance.
// Pads 8 entries past the end so attn tail batches can overrun safely.
__global__ void scatter_k(const int* __restrict__ src, const int* __restrict__ dst,
                          const float* __restrict__ attr, int* __restrict__ cursor,
                          int2* __restrict__ edat, int E)
{
    int e = blockIdx.x * 256 + threadIdx.x;
    if (e < 8) edat[E + e] = make_int2(0, 0);
    if (e < E) {
        int p = atomicAdd(&cursor[dst[e]], 1);
        edat[p] = make_int2(src[e], __float_as_int(attr[e]));
    }
}

// ---------------- attention: one wave per dst node, batched online softmax ----
// R9-MEASURED VERSION, EXACT SOURCE (100.5us, VGPR=64, SGPR=80, occ 34%).
// DO NOT REPHRASE THIS LOOP. R7 measured: rewriting the ping-pong with a
// runtime curB bool selecting buffers cost +8 VGPR (64->72) -> 7 waves/SIMD
// -> 117us. The statically-unrolled two-phase body below is load-bearing.
// HARD CONSTRAINT (R5/R6/R7): VGPR <= 64 — kernel is TLP-limited (at 64 VGPR,
// 8 waves/SIMD = architectural max occupancy).
__global__ __launch_bounds__(256) void attn_k(
    const uint2* __restrict__ q2, const uint2* __restrict__ kv8u2,
    const float* __restrict__ We,
    __half* __restrict__ hwork, const int2* __restrict__ edat,
    const int* __restrict__ offs,
    double* __restrict__ stats, int n, int nGroups)
{
    int lane = threadIdx.x & 63;
    int wid = threadIdx.x >> 6;
    float4 we = ((const float4*)We)[lane];
    float tsum = 0.f, tsq = 0.f;

    for (int g = blockIdx.x; g < nGroups; g += gridDim.x) {
        int node = g * 4 + wid;
        if (node >= n) continue;
        float4 qv = h4_to_f4(q2[(size_t)node * 256 + lane]);
        float qwe = qv.x * we.x + qv.y * we.y + qv.z * we.z + qv.w * we.w;
        qwe += __shfl_xor(qwe, 1);
        qwe += __shfl_xor(qwe, 2);
        qwe += __shfl_xor(qwe, 4);

        float4 accv = make_float4(0.f, 0.f, 0.f, 0.f);
        float sat = 0.f;
        float m = -INFINITY, l = 0.f;
        int i0 = __builtin_amdgcn_readfirstlane(offs[node]);
        int i1 = __builtin_amdgcn_readfirstlane(offs[node + 1]);

        int abA[8], srA[8], abB[8], srB[8];   // SGPR: attr bits / src index
        uint2 kvA[8], kvB[8];

        auto LOADB = [&](int base, int* ab_, int* sr_, uint2* kv_) {
#pragma unroll
            for (int u = 0; u < 8; u++) {
                int2 ed = edat[base + u];                     // uniform addr
                sr_[u] = __builtin_amdgcn_readfirstlane(ed.x);
                ab_[u] = __builtin_amdgcn_readfirstlane(ed.y);
            }
#pragma unroll
            for (int u = 0; u < 8; u++)
                kv_[u] = (kv8u2 + (size_t)(unsigned)sr_[u] * 64)[lane];
        };

        auto COMPUTE = [&](const int* ab_, const uint2* kv_, int cnt) {
            float pv[8];
#pragma unroll
            for (int u = 0; u < 8; u++) {
                float4 kvf = fp8x4_to_f4(kv_[u].x);
                float p = qv.x * kvf.x + qv.y * kvf.y + qv.z * kvf.z + qv.w * kvf.w;
                p += __shfl_xor(p, 1);
                p += __shfl_xor(p, 2);
                p += __shfl_xor(p, 4);
                p = fmaf(__int_as_float(ab_[u]), qwe, p) * 0.17677669529663687f;
                pv[u] = (u < cnt) ? p : -INFINITY;            // folds away for cnt=8
            }
            float m01 = fmaxf(pv[0], pv[1]), m23 = fmaxf(pv[2], pv[3]);
            float m45 = fmaxf(pv[4], pv[5]), m67 = fmaxf(pv[6], pv[7]);
            float pmax = fmaxf(fmaxf(m01, m23), fmaxf(m45, m67));
            float mn = fmaxf(m, pmax);
            float corr = __expf(m - mn);
            l *= corr;
            sat *= corr;
            accv.x *= corr; accv.y *= corr; accv.z *= corr; accv.w *= corr;
#pragma unroll
            for (int u = 0; u < 8; u++) {
                float wgt = __expf(pv[u] - mn);               // pad: exp(-inf)=0
                l += wgt;
                sat = fmaf(wgt, __int_as_float(ab_[u]), sat);
                float4 vv = fp8x4_to_f4(kv_[u].y);
                accv.x = fmaf(wgt, vv.x, accv.x);
                accv.y = fmaf(wgt, vv.y, accv.y);
                accv.z = fmaf(wgt, vv.z, accv.z);
                accv.w = fmaf(wgt, vv.w, accv.w);
            }
            m = mn;
        };

        if (i0 < i1) {
            int i = i0;
            LOADB(i, abA, srA, kvA);
            while (true) {
                if (i + 8 >= i1) { COMPUTE(abA, kvA, i1 - i); break; }
                LOADB(i + 8, abB, srB, kvB);
                COMPUTE(abA, kvA, 8);
                i += 8;
                if (i + 8 >= i1) { COMPUTE(abB, kvB, i1 - i); break; }
                LOADB(i + 8, abA, srA, kvA);
                COMPUTE(abB, kvB, 8);
                i += 8;
            }
        }

        float inv = (l > 0.f) ? 1.f / l : 0.f;
        float4 sk = h4_to_f4(q2[(size_t)node * 256 + 192 + lane]);
        float sw = sat * inv;
        float4 o;
        o.x = fmaf(accv.x, inv, fmaf(sw, we.x, sk.x));
        o.y = fmaf(accv.y, inv, fmaf(sw, we.y, sk.y));
        o.z = fmaf(accv.z, inv, fmaf(sw, we.z, sk.z));
        o.w = fmaf(accv.w, inv, fmaf(sw, we.w, sk.w));
        store4(hwork + (size_t)node * 256 + lane * 4, o);
        tsum += o.x + o.y + o.z + o.w;
        tsq += o.x * o.x + o.y * o.y + o.z * o.z + o.w * o.w;
    }

#pragma unroll
    for (int d = 1; d < 64; d <<= 1) {
        tsum += __shfl_xor(tsum, d);
        tsq += __shfl_xor(tsq, d);
    }
    __shared__ float red[8];
    if (lane == 0) { red[wid] = tsum; red[4 + wid] = tsq; }
    __syncthreads();
    if (threadIdx.x == 0) {
        double s = (double)red[0] + (double)red[1] + (double)red[2] + (double)red[3];
        double sq = (double)red[4] + (double)red[5] + (double)red[6] + (double)red[7];
        atomicAdd(&stats[0], s);
        atomicAdd(&stats[1], sq);
    }
}

// ---------------- LayerNorm apply (R19: per-block stats, 16B vector IO) ----------------
__global__ __launch_bounds__(256) void ln_apply(
    const uint2* __restrict__ in, __half* __restrict__ out,
    const float4* __restrict__ w4, const float4* __restrict__ b4,
    const double* __restrict__ stats, double cnt, int total4)
{
    __shared__ float sm[2];
    if (threadIdx.x == 0) {
        double mu = stats[0] / cnt;
        double var = stats[1] / cnt - mu * mu;
        if (var < 0.0) var = 0.0;
        sm[0] = (float)mu;
        sm[1] = (float)(1.0 / (sqrt(var) + (double)EPSLN));
    }
    __syncthreads();
    int base = (blockIdx.x * 256 + threadIdx.x) * 4;
    if (base >= total4) return;
    float mean = sm[0];
    float inv = sm[1];

    uint4 ra = *(const uint4*)(in + base);        // i = base, base+1
    uint4 rb = *(const uint4*)(in + base + 2);    // i = base+2, base+3
    uint2 rw[4] = { make_uint2(ra.x, ra.y), make_uint2(ra.z, ra.w),
                    make_uint2(rb.x, rb.y), make_uint2(rb.z, rb.w) };
    uint2 ow[4];
#pragma unroll
    for (int u = 0; u < 4; u++) {
        int i = base + u;
        int c = i & 63;
        float4 xv = h4_to_f4(rw[u]);
        float4 w = w4[c], b = b4[c];
        float4 o;
        o.x = fmaf((xv.x - mean) * inv, w.x, b.x);
        o.y = fmaf((xv.y - mean) * inv, w.y, b.y);
        o.z = fmaf((xv.z - mean) * inv, w.z, b.z);
        o.w = fmaf((xv.w - mean) * inv, w.w, b.w);
        o.x = o.x > 0.f ? o.x : expm1f(o.x);
        o.y = o.y > 0.f ? o.y : expm1f(o.y);
        o.z = o.z > 0.f ? o.z : expm1f(o.z);
        o.w = o.w > 0.f ? o.w : expm1f(o.w);
        union { uint2 u2; __half2 h[2]; } s;
        s.h[0] = __floats2half2_rn(o.x, o.y);
        s.h[1] = __floats2half2_rn(o.z, o.w);
        ow[u] = s.u2;
    }
    uint4 s0 = make_uint4(ow[0].x, ow[0].y, ow[1].x, ow[1].y);
    uint4 s1 = make_uint4(ow[2].x, ow[2].y, ow[3].x, ow[3].y);
    *(uint4*)(out + (size_t)base * 4) = s0;
    *(uint4*)(out + (size_t)(base + 2) * 4) = s1;
}

// ---------------- driver ----------------
extern "C" void kernel_launch(void* const* d_in, const int* in_sizes, int n_in,
                              void* d_out, int out_size, void* d_ws, size_t ws_size,
                              hipStream_t stream)
{
    const float* x      = (const float*)d_in[0];
    const int*   ei     = (const int*)d_in[1];
    const float* eattr  = (const float*)d_in[2];
    const float* Wq1 = (const float*)d_in[3];  const float* bq1 = (const float*)d_in[4];
    const float* Wk1 = (const float*)d_in[5];  const float* bk1 = (const float*)d_in[6];
    const float* Wv1 = (const float*)d_in[7];  const float* bv1 = (const float*)d_in[8];
    const float* We1 = (const float*)d_in[9];
    const float* Ws1 = (const float*)d_in[10]; const float* bs1 = (const float*)d_in[11];
    const float* lnw1 = (const float*)d_in[12]; const float* lnb1 = (const float*)d_in[13];
    const float* Wq2 = (const float*)d_in[14]; const float* bq2 = (const float*)d_in[15];
    const float* Wk2 = (const float*)d_in[16]; const float* bk2 = (const float*)d_in[17];
    const float* Wv2 = (const float*)d_in[18]; const float* bv2 = (const float*)d_in[19];
    const float* We2 = (const float*)d_in[20];
    const float* Ws2 = (const float*)d_in[21]; const float* bs2 = (const float*)d_in[22];
    const float* lnw2 = (const float*)d_in[23]; const float* lnb2 = (const float*)d_in[24];
    const float* Wo  = (const float*)d_in[25]; const float* bo  = (const float*)d_in[26];

    const int N = in_sizes[0] / IN_DIM;
    const int E = in_sizes[2];
    const int* esrc = ei;
    const int* edst = ei + E;

    char* ws = (char*)d_ws;
    size_t off = 0;
    auto alloc = [&](size_t bytes) -> char* {
        char* p = ws + off;
        off += (bytes + 255) / 256 * 256;
        return p;
    };
    int*    counts = (int*)alloc((size_t)N * 4);
    double* stats  = (double*)alloc(64);
    size_t zbytes = off;
    int*    cursor = (int*)alloc((size_t)N * 4);
    int*    offs   = (int*)alloc((size_t)(N + 1) * 4);
    int2*   edat   = (int2*)alloc((size_t)(E + 8) * 8);
    __half* xh     = (__half*)alloc((size_t)N * IN_DIM * 2);
    __half* qkvs   = (__half*)alloc((size_t)N * 1024 * 2);
    unsigned char* kv8 = (unsigned char*)alloc((size_t)N * 512);
    __half* hwork  = (__half*)alloc((size_t)N * HD * 2);
    __half* hio    = (__half*)alloc((size_t)N * HD * 2);
    __half* Wc1    = (__half*)alloc((size_t)1024 * IN_DIM * 2);
    __half* Wc2    = (__half*)alloc((size_t)1024 * HD * 2);
    __half* Wot    = (__half*)alloc((size_t)64 * HD * 2);
    float*  bc1    = (float*)alloc(1024 * 4);
    float*  bc2    = (float*)alloc(1024 * 4);
    int*    part   = (int*)alloc(512);            // scan partials (<=128 blocks)

    hipMemsetAsync(d_ws, 0, zbytes, stream);

    int total4x = N * (IN_DIM / 4);
    int prepWork = total4x > E ? total4x : E;
    if (prepWork < 411648) prepWork = 411648;
    prep_k<<<(prepWork + 255) / 256, 256, 0, stream>>>(
        (const float4*)x, xh, total4x, edst, counts, E,
        Wq1, Wk1, Wv1, Ws1, Wq2, Wk2, Wv2, Ws2, Wo,
        bq1, bk1, bv1, bs1, bq2, bk2, bv2, bs2,
        Wc1, Wc2, Wot, bc1, bc2);

    int nblkS = (N + 511) / 512;                  // 98 for N=50000 (<=128 req'd)
    scan_part_k<<<nblkS, 256, 0, stream>>>(counts, part, N);
    scan_top_k<<<1, 128, 0, stream>>>(part, nblkS);
    scan_fix_k<<<nblkS, 256, 0, stream>>>(counts, part, offs, cursor, N);
    scatter_k<<<(E + 255) / 256, 256, 0, stream>>>(esrc, edst, eattr, cursor,
                                                   edat, E);

    int nbx = (N + BM - 1) / BM;
    dim3 gqkvs(nbx * 8);                              // 1-D grid for XCD swizzle
    int nGroups = (N + 3) / 4;
    int gaBlocks = nGroups < 2048 ? nGroups : 2048;   // persistent blocks (proven R8 config)
    int total4 = N * (HD / 4);
    dim3 gl((total4 / 4 + 255) / 256);
    dim3 gout((N + 127) / 128);

    // ---- layer 1 ----
    gemm_mfma<<<gqkvs, 256, 0, stream>>>(xh, Wc1, bc1, qkvs, kv8, N, IN_DIM, 1024);
    attn_k<<<gaBlocks, 256, 0, stream>>>((const uint2*)qkvs, (const uint2*)kv8, We1,
                                         hwork, edat, offs, stats, N, nGroups);
    ln_apply<<<gl, 256, 0, stream>>>((const uint2*)hwork, hio,
                                     (const float4*)lnw1, (const float4*)lnb1,
                                     stats, (double)N * HD, total4);

    // ---- layer 2 ----
    gemm_mfma<<<gqkvs, 256, 0, stream>>>(hio, Wc2, bc2, qkvs, kv8, N, HD, 1024);
    attn_k<<<gaBlocks, 256, 0, stream>>>((const uint2*)qkvs, (const uint2*)kv8, We2,
                                         hwork, edat, offs, stats + 2, N, nGroups);
    ln_apply<<<gl, 256, 0, stream>>>((const uint2*)hwork, hio,
                                     (const float4*)lnw2, (const float4*)lnb2,
                                     stats + 2, (double)N * HD, total4);

    // ---- output projection (fp32 out, dedicated 128x64 kernel) ----
    gemm_out_k<<<gout, 256, 0, stream>>>(hio, Wot, bo, (float*)d_out, N);
}

// Round 15
// 515.478 us; speedup vs baseline: 1.0078x; 1.0078x over previous
//
#include <hip/hip_runtime.h>
#include <hip/hip_fp16.h>
#include <math.h>

#define IN_DIM 128
#define HD 256
#define EPSLN 1e-5f

typedef _Float16 half8 __attribute__((ext_vector_type(8)));
typedef float f32x4 __attribute__((ext_vector_type(4)));
typedef float f32x2 __attribute__((ext_vector_type(2)));

// ---------------- helpers ----------------
__device__ inline void store4(float* p, float4 o) { *(float4*)p = o; }
__device__ inline void store4(__half* p, float4 o) {
    union { uint2 u; __half2 h[2]; } s;
    s.h[0] = __floats2half2_rn(o.x, o.y);
    s.h[1] = __floats2half2_rn(o.z, o.w);
    *(uint2*)p = s.u;
}
__device__ inline float4 h4_to_f4(uint2 u) {
    union { unsigned int w; __half2 h; } a, b;
    a.w = u.x; b.w = u.y;
    float2 lo = __half22float2(a.h), hi = __half22float2(b.h);
    return make_float4(lo.x, lo.y, hi.x, hi.y);
}
// 4 floats -> 4 packed fp8 e4m3 (OCP, gfx950 HW cvt)
__device__ inline unsigned int f4_to_fp8x4(float a, float b, float c, float d) {
    int v = 0;
    v = __builtin_amdgcn_cvt_pk_fp8_f32(a, b, v, false);
    v = __builtin_amdgcn_cvt_pk_fp8_f32(c, d, v, true);
    return (unsigned int)v;
}
__device__ inline float4 fp8x4_to_f4(unsigned int u) {
    f32x2 lo = __builtin_amdgcn_cvt_pk_f32_fp8((int)u, false);
    f32x2 hi = __builtin_amdgcn_cvt_pk_f32_fp8((int)u, true);
    return make_float4(lo.x, lo.y, hi.x, hi.y);
}

__device__ inline void async_copy16(const __half* g, _Float16* l) {
    __builtin_amdgcn_global_load_lds(
        (const __attribute__((address_space(1))) void*)g,
        (__attribute__((address_space(3))) void*)l,
        16, 0, 0);
}

// Packed output column mapping: q[0:256) | kv-interleaved[256:768) | skip[768:1024)
__device__ inline void unpermute_col(int n, int& sel, int& c) {
    if (n < 256) { sel = 0; c = n; }
    else if (n < 768) {
        int j = n - 256, chunk = j >> 3, w = j & 7;
        if (w < 4) { sel = 1; c = chunk * 4 + w; }
        else       { sel = 2; c = chunk * 4 + w - 4; }
    } else { sel = 3; c = n - 768; }
}

// ---------------- fused prep: pack x, pack weights/biases, count degrees ----
// R20: counts atomic is FIRE-AND-FORGET (no return -> no per-wave dependency
// chain); slot claim moved to scatter_k's cursor atomic; rank array deleted.
__global__ void prep_k(
    const float4* __restrict__ x, __half* __restrict__ xh, int total4,
    const int* __restrict__ dst, int* __restrict__ counts, int E,
    const float* __restrict__ Wq1, const float* __restrict__ Wk1,
    const float* __restrict__ Wv1, const float* __restrict__ Ws1,
    const float* __restrict__ Wq2, const float* __restrict__ Wk2,
    const float* __restrict__ Wv2, const float* __restrict__ Ws2,
    const float* __restrict__ Wo,
    const float* __restrict__ bq1, const float* __restrict__ bk1,
    const float* __restrict__ bv1, const float* __restrict__ bs1,
    const float* __restrict__ bq2, const float* __restrict__ bk2,
    const float* __restrict__ bv2, const float* __restrict__ bs2,
    __half* __restrict__ Wc1, __half* __restrict__ Wc2, __half* __restrict__ Wot,
    float* __restrict__ bc1, float* __restrict__ bc2)
{
    int idx = blockIdx.x * 256 + threadIdx.x;
    if (idx < total4) store4(xh + (size_t)idx * 4, x[idx]);
    if (idx < E) atomicAdd(&counts[dst[idx]], 1);   // histogram only, no return
    if (idx < 131072) {
        int n = idx >> 7, k = idx & 127;
        int sel, c; unpermute_col(n, sel, c);
        const float* W = (sel == 0) ? Wq1 : (sel == 1) ? Wk1 : (sel == 2) ? Wv1 : Ws1;
        Wc1[idx] = __float2half(W[(size_t)k * 256 + c]);
    } else if (idx < 393216) {
        int j = idx - 131072;
        int n = j >> 8, k = j & 255;
        int sel, c; unpermute_col(n, sel, c);
        const float* W = (sel == 0) ? Wq2 : (sel == 1) ? Wk2 : (sel == 2) ? Wv2 : Ws2;
        Wc2[j] = __float2half(W[(size_t)k * 256 + c]);
    } else if (idx < 409600) {
        int j = idx - 393216;
        int n = j >> 8, k = j & 255;
        Wot[j] = __float2half(Wo[(size_t)k * 64 + n]);
    } else if (idx < 410624) {
        int n = idx - 409600;
        int sel, c; unpermute_col(n, sel, c);
        const float* b = (sel == 0) ? bq1 : (sel == 1) ? bk1 : (sel == 2) ? bv1 : bs1;
        bc1[n] = b[c];
    } else if (idx < 411648) {
        int n = idx - 410624;
        int sel, c; unpermute_col(n, sel, c);
        const float* b = (sel == 0) ? bq2 : (sel == 1) ? bk2 : (sel == 2) ? bv2 : bs2;
        bc2[n] = b[c];
    }
}

// ---------------- MFMA GEMM: C[M x Nc] = A[M x K] @ Wt^T + bias (f16 out) ----------------
// R13: 1-D grid + XCD-grouping swizzle (measured R4: ~44us win across both gemms).
// R17/R18: BK=32 single-barrier double-buffer (measured R11: neutral; kept as
// the verified config). LDS: As0@0, Bs0@8K, As1@16K, Bs1@24K within the
// 34,816B epilogue region. Buffer bases computed per-use (LDS pointer arrays
// fail to compile on gfx950 — R10 lesson).
#define BM 128
#define BN 128
#define TROWB 272   // f16 out-tile row stride (bytes)

__global__ __launch_bounds__(256) void gemm_mfma(
    const __half* __restrict__ A, const __half* __restrict__ Wt,
    const float* __restrict__ bias, __half* __restrict__ C,
    unsigned char* __restrict__ kv8,
    int M, int K, int Nc)
{
    __shared__ char smem[BM * TROWB];          // 34,816 B; dbuf overlaid below

    int tid = threadIdx.x;
    int lane = tid & 63, w = tid >> 6;
    int wm = w >> 1, wn = w & 1;
    int quad = lane >> 4, l16 = lane & 15;
    // XCD swizzle: nwg = nbx*8 (exact multiple of 8 XCDs)
    int nbx = (int)gridDim.x >> 3;
    int wkr = ((int)blockIdx.x & 7) * nbx + ((int)blockIdx.x >> 3);
    int row0 = (wkr >> 3) * BM;
    int col0 = (wkr & 7) * BN;

    f32x4 acc[4][4];
#pragma unroll
    for (int i = 0; i < 4; i++)
#pragma unroll
        for (int j = 0; j < 4; j++) acc[i][j] = (f32x4){0.f, 0.f, 0.f, 0.f};

    int srow = lane >> 2;      // 0..15 (16 rows per wave-instruction at BK=32)
    int schunk = lane & 3;     // 4 chunks of 8 f16 per 64B row

    int nt = K >> 5;           // K/32 steps

    // STAGE(step, buf): issue A+B tile loads for k0 = step*32 into buffer buf
    auto STAGE = [&](int step, int buf) {
        int k0 = step << 5;
        _Float16* Asb = (_Float16*)(smem + buf * 16384);
        _Float16* Bsb = (_Float16*)(smem + 8192 + buf * 16384);
#pragma unroll
        for (int t = 0; t < 2; t++) {
            int r = w * 32 + t * 16 + srow;
            int gr = row0 + r; if (gr > M - 1) gr = M - 1;
            int gchunk = schunk ^ ((r ^ (r >> 2)) & 3);
            async_copy16(&A[(size_t)gr * K + k0 + gchunk * 8], &Asb[(w * 32 + t * 16) * 32]);
        }
#pragma unroll
        for (int t = 0; t < 2; t++) {
            int r = w * 32 + t * 16 + srow;
            int gc = col0 + r; if (gc > Nc - 1) gc = Nc - 1;
            int gchunk = schunk ^ ((r ^ (r >> 2)) & 3);
            async_copy16(&Wt[(size_t)gc * K + k0 + gchunk * 8], &Bsb[(w * 32 + t * 16) * 32]);
        }
    };

    STAGE(0, 0);
    __syncthreads();

    for (int t = 0; t < nt; ++t) {
        if (t + 1 < nt) STAGE(t + 1, (t + 1) & 1);
        _Float16* Asb = (_Float16*)(smem + (t & 1) * 16384);
        _Float16* Bsb = (_Float16*)(smem + 8192 + (t & 1) * 16384);
        half8 af[4], bf[4];
#pragma unroll
        for (int i = 0; i < 4; i++) {
            int ra = wm * 64 + i * 16 + l16;
            af[i] = *(half8*)&Asb[ra * 32 + ((quad ^ ((ra ^ (ra >> 2)) & 3)) * 8)];
            int rb = wn * 64 + i * 16 + l16;
            bf[i] = *(half8*)&Bsb[rb * 32 + ((quad ^ ((rb ^ (rb >> 2)) & 3)) * 8)];
        }
#pragma unroll
        for (int i = 0; i < 4; i++)
#pragma unroll
            for (int j = 0; j < 4; j++)
                acc[i][j] = __builtin_amdgcn_mfma_f32_16x16x32_f16(af[i], bf[j], acc[i][j], 0, 0, 0);
        __syncthreads();
    }

#pragma unroll
    for (int j = 0; j < 4; j++) {
        int tcol = wn * 64 + j * 16 + l16;
        float bb = (col0 + tcol < Nc) ? bias[col0 + tcol] : 0.f;
#pragma unroll
        for (int i = 0; i < 4; i++) {
#pragma unroll
            for (int r = 0; r < 4; r++) {
                int trow = wm * 64 + i * 16 + quad * 4 + r;
                ((__half*)(smem + trow * TROWB))[tcol] = __float2half(acc[i][j][r] + bb);
            }
        }
    }
    __syncthreads();
    bool iskv = (col0 >= 256) && (col0 < 768);
    int crow = tid >> 4, cchunk = tid & 15;
    for (int p = 0; p < 8; p++) {
        int trow = p * 16 + crow;
        int grow = row0 + trow;
        if (grow >= M) continue;
        uint4 val = *(uint4*)(smem + trow * TROWB + cchunk * 16);
        if (iskv) {
            float4 lo = h4_to_f4(make_uint2(val.x, val.y));
            float4 hi = h4_to_f4(make_uint2(val.z, val.w));
            uint2 o8;
            o8.x = f4_to_fp8x4(lo.x, lo.y, lo.z, lo.w);
            o8.y = f4_to_fp8x4(hi.x, hi.y, hi.z, hi.w);
            *(uint2*)&kv8[(size_t)grow * 512 + (col0 - 256) + cchunk * 8] = o8;
        } else {
            *(uint4*)&C[(size_t)grow * Nc + col0 + cchunk * 8] = val;
        }
    }
}

// ---------------- output GEMM: D[M x 64] = A[M x 256] @ Wot^T + bo (fp32 out) ----------
// R17/R18: BK=32 single-barrier double-buffer. LDS 24KB.
// Layout (halfs): As0@0 (4096), As1@4096, Bs0@8192 (2048), Bs1@10240.
__global__ __launch_bounds__(256) void gemm_out_k(
    const __half* __restrict__ A, const __half* __restrict__ Wot,
    const float* __restrict__ bias, float* __restrict__ D, int M)
{
    __shared__ _Float16 smem[12288];   // 24 KB
    int tid = threadIdx.x;
    int lane = tid & 63, w = tid >> 6;
    int quad = lane >> 4, l16 = lane & 15;
    int row0 = blockIdx.x * 128;
    const int K = 256;

    f32x4 acc[2][4];
#pragma unroll
    for (int i = 0; i < 2; i++)
#pragma unroll
        for (int j = 0; j < 4; j++) acc[i][j] = (f32x4){0.f, 0.f, 0.f, 0.f};

    int srow = lane >> 2;
    int schunk = lane & 3;
    const int nt = 8;   // 256/32

    auto STAGE = [&](int step, int buf) {
        int k0 = step << 5;
        _Float16* Asb = smem + buf * 4096;
        _Float16* Bsb = smem + 8192 + buf * 2048;
#pragma unroll
        for (int t = 0; t < 2; t++) {
            int r = w * 32 + t * 16 + srow;
            int gr = row0 + r; if (gr > M - 1) gr = M - 1;
            int gchunk = schunk ^ ((r ^ (r >> 2)) & 3);
            async_copy16(&A[(size_t)gr * K + k0 + gchunk * 8], &Asb[(w * 32 + t * 16) * 32]);
        }
        {
            int r = w * 16 + srow;       // 64 weight rows, one wave-inst per wave
            int gchunk = schunk ^ ((r ^ (r >> 2)) & 3);
            async_copy16(&Wot[(size_t)r * K + k0 + gchunk * 8], &Bsb[(w * 16) * 32]);
        }
    };

    STAGE(0, 0);
    __syncthreads();

    for (int t = 0; t < nt; ++t) {
        if (t + 1 < nt) STAGE(t + 1, (t + 1) & 1);
        _Float16* Asb = smem + (t & 1) * 4096;
        _Float16* Bsb = smem + 8192 + (t & 1) * 2048;
        half8 af[2], bf[4];
#pragma unroll
        for (int i = 0; i < 2; i++) {
            int ra = w * 32 + i * 16 + l16;
            af[i] = *(half8*)&Asb[ra * 32 + ((quad ^ ((ra ^ (ra >> 2)) & 3)) * 8)];
        }
#pragma unroll
        for (int j = 0; j < 4; j++) {
            int rb = j * 16 + l16;
            bf[j] = *(half8*)&Bsb[rb * 32 + ((quad ^ ((rb ^ (rb >> 2)) & 3)) * 8)];
        }
#pragma unroll
        for (int i = 0; i < 2; i++)
#pragma unroll
            for (int j = 0; j < 4; j++)
                acc[i][j] = __builtin_amdgcn_mfma_f32_16x16x32_f16(af[i], bf[j], acc[i][j], 0, 0, 0);
        __syncthreads();
    }

#pragma unroll
    for (int i = 0; i < 2; i++) {
#pragma unroll
        for (int j = 0; j < 4; j++) {
            int gcol = j * 16 + l16;
            float bb = bias[gcol];
#pragma unroll
            for (int r = 0; r < 4; r++) {
                int grow = row0 + w * 32 + i * 16 + quad * 4 + r;
                if (grow < M) D[(size_t)grow * 64 + gcol] = acc[i][j][r] + bb;
            }
        }
    }
}

// ---------------- edge bucketing: 2-phase parallel scan (R21) ----------------
// R19 measured the parallel scan at -87us vs single-block serial. R21 fuses
// the 128-thread top-prefix INTO scan_fix: each of the 98 blocks redundantly
// reduces part[j<b] to its own base (~98 loads/block, trivial) — one fewer
// launch + gap.
__global__ __launch_bounds__(256) void scan_part_k(const int* __restrict__ counts,
                                                   int* __restrict__ part, int n)
{
    int b = blockIdx.x, t = threadIdx.x;
    int i0 = b * 512 + t * 2;
    int s = 0;
    if (i0 < n) s += counts[i0];
    if (i0 + 1 < n) s += counts[i0 + 1];
    int lane = t & 63, wid = t >> 6;
    int v = s;
#pragma unroll
    for (int d = 1; d < 64; d <<= 1) v += __shfl_xor(v, d);
    __shared__ int ws[4];
    if (lane == 0) ws[wid] = v;
    __syncthreads();
    if (t == 0) part[b] = ws[0] + ws[1] + ws[2] + ws[3];
}

// R20: emits cursor[] (copy of exclusive prefix) for scatter_k's slot-claims.
// R21: computes its own block base from raw part[] sums (top-scan fused).
__global__ __launch_bounds__(256) void scan_fix_k(const int* __restrict__ counts,
                                                  const int* __restrict__ part,
                                                  int* __restrict__ offs,
                                                  int* __restrict__ cursor, int n)
{
    __shared__ int sbase[2];
    int b = blockIdx.x, t = threadIdx.x;
    int lane = t & 63, wid = t >> 6;
    // block base = sum of part[j] for j < b (b <= 127; threads 0-127 help)
    {
        int pv = (t < b) ? part[t] : 0;      // b<=127 so t<128 covers all
        int vv = pv;
#pragma unroll
        for (int d = 1; d < 64; d <<= 1) vv += __shfl_xor(vv, d);
        if (lane == 0 && wid < 2) sbase[wid] = vv;
        __syncthreads();
    }
    int base = sbase[0] + sbase[1];

    int i0 = b * 512 + t * 2;
    int c0 = (i0 < n) ? counts[i0] : 0;
    int c1 = (i0 + 1 < n) ? counts[i0 + 1] : 0;
    int s = c0 + c1;
    int v = s;
#pragma unroll
    for (int d = 1; d < 64; d <<= 1) {
        int u = __shfl_up(v, (unsigned)d, 64);
        if (lane >= d) v += u;
    }
    __shared__ int wsum[4], wpre[4];
    if (lane == 63) wsum[wid] = v;
    __syncthreads();
    if (t == 0) { int a = 0; for (int i = 0; i < 4; i++) { wpre[i] = a; a += wsum[i]; } }
    __syncthreads();
    int pre = base + wpre[wid] + v - s;   // exclusive prefix for this thread
    if (i0 < n) { offs[i0] = pre; cursor[i0] = pre; }
    if (i0 + 1 < n) { offs[i0 + 1] = pre + c0; cursor[i0 + 1] = pre + c0; }
    int end = i0 + 2; if (end > n) end = n;
    if (end == n) offs[n] = pre + c0 + c1;   // racing writers all write the total
}

// R20: slot claim via cursor atomic. R21: 2 edges/thread (half the blocks).
// Bucket order arbitrary; attn's online softmax is order-independent.
// Pads 8 entries past the end so attn tail batches can overrun safely.
__global__ void scatter_k(const int* __restrict__ src, const int* __restrict__ dst,
                          const float* __restrict__ attr, int* __restrict__ cursor,
                          int2* __restrict__ edat, int E)
{
    int g = blockIdx.x * 256 + threadIdx.x;
    if (g < 8) edat[E + g] = make_int2(0, 0);
    int e0 = g * 2;
#pragma unroll
    for (int u = 0; u < 2; u++) {
        int e = e0 + u;
        if (e < E) {
            int p = atomicAdd(&cursor[dst[e]], 1);
            edat[p] = make_int2(src[e], __float_as_int(attr[e]));
        }
    }
}

// ---------------- attention: one wave per dst node, batched online softmax ----
// R9-MEASURED VERSION, EXACT SOURCE (100.5us fast-container / 109.5 slow,
// VGPR=64, SGPR=80, occ 34%). DO NOT REPHRASE THIS LOOP (R7: +8 VGPR -> -9%).
// HARD CONSTRAINT (R5/R6/R7): VGPR <= 64 — TLP-limited at the 8-waves/SIMD max.
// This kernel is the cross-run clock canary: normalize totals by its dur.
__global__ __launch_bounds__(256) void attn_k(
    const uint2* __restrict__ q2, const uint2* __restrict__ kv8u2,
    const float* __restrict__ We,
    __half* __restrict__ hwork, const int2* __restrict__ edat,
    const int* __restrict__ offs,
    double* __restrict__ stats, int n, int nGroups)
{
    int lane = threadIdx.x & 63;
    int wid = threadIdx.x >> 6;
    float4 we = ((const float4*)We)[lane];
    float tsum = 0.f, tsq = 0.f;

    for (int g = blockIdx.x; g < nGroups; g += gridDim.x) {
        int node = g * 4 + wid;
        if (node >= n) continue;
        float4 qv = h4_to_f4(q2[(size_t)node * 256 + lane]);
        float qwe = qv.x * we.x + qv.y * we.y + qv.z * we.z + qv.w * we.w;
        qwe += __shfl_xor(qwe, 1);
        qwe += __shfl_xor(qwe, 2);
        qwe += __shfl_xor(qwe, 4);

        float4 accv = make_float4(0.f, 0.f, 0.f, 0.f);
        float sat = 0.f;
        float m = -INFINITY, l = 0.f;
        int i0 = __builtin_amdgcn_readfirstlane(offs[node]);
        int i1 = __builtin_amdgcn_readfirstlane(offs[node + 1]);

        int abA[8], srA[8], abB[8], srB[8];   // SGPR: attr bits / src index
        uint2 kvA[8], kvB[8];

        auto LOADB = [&](int base, int* ab_, int* sr_, uint2* kv_) {
#pragma unroll
            for (int u = 0; u < 8; u++) {
                int2 ed = edat[base + u];                     // uniform addr
                sr_[u] = __builtin_amdgcn_readfirstlane(ed.x);
                ab_[u] = __builtin_amdgcn_readfirstlane(ed.y);
            }
#pragma unroll
            for (int u = 0; u < 8; u++)
                kv_[u] = (kv8u2 + (size_t)(unsigned)sr_[u] * 64)[lane];
        };

        auto COMPUTE = [&](const int* ab_, const uint2* kv_, int cnt) {
            float pv[8];
#pragma unroll
            for (int u = 0; u < 8; u++) {
                float4 kvf = fp8x4_to_f4(kv_[u].x);
                float p = qv.x * kvf.x + qv.y * kvf.y + qv.z * kvf.z + qv.w * kvf.w;
                p += __shfl_xor(p, 1);
                p += __shfl_xor(p, 2);
                p += __shfl_xor(p, 4);
                p = fmaf(__int_as_float(ab_[u]), qwe, p) * 0.17677669529663687f;
                pv[u] = (u < cnt) ? p : -INFINITY;            // folds away for cnt=8
            }
            float m01 = fmaxf(pv[0], pv[1]), m23 = fmaxf(pv[2], pv[3]);
            float m45 = fmaxf(pv[4], pv[5]), m67 = fmaxf(pv[6], pv[7]);
            float pmax = fmaxf(fmaxf(m01, m23), fmaxf(m45, m67));
            float mn = fmaxf(m, pmax);
            float corr = __expf(m - mn);
            l *= corr;
            sat *= corr;
            accv.x *= corr; accv.y *= corr; accv.z *= corr; accv.w *= corr;
#pragma unroll
            for (int u = 0; u < 8; u++) {
                float wgt = __expf(pv[u] - mn);               // pad: exp(-inf)=0
                l += wgt;
                sat = fmaf(wgt, __int_as_float(ab_[u]), sat);
                float4 vv = fp8x4_to_f4(kv_[u].y);
                accv.x = fmaf(wgt, vv.x, accv.x);
                accv.y = fmaf(wgt, vv.y, accv.y);
                accv.z = fmaf(wgt, vv.z, accv.z);
                accv.w = fmaf(wgt, vv.w, accv.w);
            }
            m = mn;
        };

        if (i0 < i1) {
            int i = i0;
            LOADB(i, abA, srA, kvA);
            while (true) {
                if (i + 8 >= i1) { COMPUTE(abA, kvA, i1 - i); break; }
                LOADB(i + 8, abB, srB, kvB);
                COMPUTE(abA, kvA, 8);
                i += 8;
                if (i + 8 >= i1) { COMPUTE(abB, kvB, i1 - i); break; }
                LOADB(i + 8, abA, srA, kvA);
                COMPUTE(abB, kvB, 8);
                i += 8;
            }
        }

        float inv = (l > 0.f) ? 1.f / l : 0.f;
        float4 sk = h4_to_f4(q2[(size_t)node * 256 + 192 + lane]);
        float sw = sat * inv;
        float4 o;
        o.x = fmaf(accv.x, inv, fmaf(sw, we.x, sk.x));
        o.y = fmaf(accv.y, inv, fmaf(sw, we.y, sk.y));
        o.z = fmaf(accv.z, inv, fmaf(sw, we.z, sk.z));
        o.w = fmaf(accv.w, inv, fmaf(sw, we.w, sk.w));
        store4(hwork + (size_t)node * 256 + lane * 4, o);
        tsum += o.x + o.y + o.z + o.w;
        tsq += o.x * o.x + o.y * o.y + o.z * o.z + o.w * o.w;
    }

#pragma unroll
    for (int d = 1; d < 64; d <<= 1) {
        tsum += __shfl_xor(tsum, d);
        tsq += __shfl_xor(tsq, d);
    }
    __shared__ float red[8];
    if (lane == 0) { red[wid] = tsum; red[4 + wid] = tsq; }
    __syncthreads();
    if (threadIdx.x == 0) {
        double s = (double)red[0] + (double)red[1] + (double)red[2] + (double)red[3];
        double sq = (double)red[4] + (double)red[5] + (double)red[6] + (double)red[7];
        atomicAdd(&stats[0], s);
        atomicAdd(&stats[1], sq);
    }
}

// ---------------- LayerNorm apply (R19: per-block stats, 16B vector IO) ----------------
__global__ __launch_bounds__(256) void ln_apply(
    const uint2* __restrict__ in, __half* __restrict__ out,
    const float4* __restrict__ w4, const float4* __restrict__ b4,
    const double* __restrict__ stats, double cnt, int total4)
{
    __shared__ float sm[2];
    if (threadIdx.x == 0) {
        double mu = stats[0] / cnt;
        double var = stats[1] / cnt - mu * mu;
        if (var < 0.0) var = 0.0;
        sm[0] = (float)mu;
        sm[1] = (float)(1.0 / (sqrt(var) + (double)EPSLN));
    }
    __syncthreads();
    int base = (blockIdx.x * 256 + threadIdx.x) * 4;
    if (base >= total4) return;
    float mean = sm[0];
    float inv = sm[1];

    uint4 ra = *(const uint4*)(in + base);        // i = base, base+1
    uint4 rb = *(const uint4*)(in + base + 2);    // i = base+2, base+3
    uint2 rw[4] = { make_uint2(ra.x, ra.y), make_uint2(ra.z, ra.w),
                    make_uint2(rb.x, rb.y), make_uint2(rb.z, rb.w) };
    uint2 ow[4];
#pragma unroll
    for (int u = 0; u < 4; u++) {
        int i = base + u;
        int c = i & 63;
        float4 xv = h4_to_f4(rw[u]);
        float4 w = w4[c], b = b4[c];
        float4 o;
        o.x = fmaf((xv.x - mean) * inv, w.x, b.x);
        o.y = fmaf((xv.y - mean) * inv, w.y, b.y);
        o.z = fmaf((xv.z - mean) * inv, w.z, b.z);
        o.w = fmaf((xv.w - mean) * inv, w.w, b.w);
        o.x = o.x > 0.f ? o.x : expm1f(o.x);
        o.y = o.y > 0.f ? o.y : expm1f(o.y);
        o.z = o.z > 0.f ? o.z : expm1f(o.z);
        o.w = o.w > 0.f ? o.w : expm1f(o.w);
        union { uint2 u2; __half2 h[2]; } s;
        s.h[0] = __floats2half2_rn(o.x, o.y);
        s.h[1] = __floats2half2_rn(o.z, o.w);
        ow[u] = s.u2;
    }
    uint4 s0 = make_uint4(ow[0].x, ow[0].y, ow[1].x, ow[1].y);
    uint4 s1 = make_uint4(ow[2].x, ow[2].y, ow[3].x, ow[3].y);
    *(uint4*)(out + (size_t)base * 4) = s0;
    *(uint4*)(out + (size_t)(base + 2) * 4) = s1;
}

// ---------------- driver ----------------
extern "C" void kernel_launch(void* const* d_in, const int* in_sizes, int n_in,
                              void* d_out, int out_size, void* d_ws, size_t ws_size,
                              hipStream_t stream)
{
    const float* x      = (const float*)d_in[0];
    const int*   ei     = (const int*)d_in[1];
    const float* eattr  = (const float*)d_in[2];
    const float* Wq1 = (const float*)d_in[3];  const float* bq1 = (const float*)d_in[4];
    const float* Wk1 = (const float*)d_in[5];  const float* bk1 = (const float*)d_in[6];
    const float* Wv1 = (const float*)d_in[7];  const float* bv1 = (const float*)d_in[8];
    const float* We1 = (const float*)d_in[9];
    const float* Ws1 = (const float*)d_in[10]; const float* bs1 = (const float*)d_in[11];
    const float* lnw1 = (const float*)d_in[12]; const float* lnb1 = (const float*)d_in[13];
    const float* Wq2 = (const float*)d_in[14]; const float* bq2 = (const float*)d_in[15];
    const float* Wk2 = (const float*)d_in[16]; const float* bk2 = (const float*)d_in[17];
    const float* Wv2 = (const float*)d_in[18]; const float* bv2 = (const float*)d_in[19];
    const float* We2 = (const float*)d_in[20];
    const float* Ws2 = (const float*)d_in[21]; const float* bs2 = (const float*)d_in[22];
    const float* lnw2 = (const float*)d_in[23]; const float* lnb2 = (const float*)d_in[24];
    const float* Wo  = (const float*)d_in[25]; const float* bo  = (const float*)d_in[26];

    const int N = in_sizes[0] / IN_DIM;
    const int E = in_sizes[2];
    const int* esrc = ei;
    const int* edst = ei + E;

    char* ws = (char*)d_ws;
    size_t off = 0;
    auto alloc = [&](size_t bytes) -> char* {
        char* p = ws + off;
        off += (bytes + 255) / 256 * 256;
        return p;
    };
    int*    counts = (int*)alloc((size_t)N * 4);
    double* stats  = (double*)alloc(64);
    size_t zbytes = off;
    int*    cursor = (int*)alloc((size_t)N * 4);
    int*    offs   = (int*)alloc((size_t)(N + 1) * 4);
    int2*   edat   = (int2*)alloc((size_t)(E + 8) * 8);
    __half* xh     = (__half*)alloc((size_t)N * IN_DIM * 2);
    __half* qkvs   = (__half*)alloc((size_t)N * 1024 * 2);
    unsigned char* kv8 = (unsigned char*)alloc((size_t)N * 512);
    __half* hwork  = (__half*)alloc((size_t)N * HD * 2);
    __half* hio    = (__half*)alloc((size_t)N * HD * 2);
    __half* Wc1    = (__half*)alloc((size_t)1024 * IN_DIM * 2);
    __half* Wc2    = (__half*)alloc((size_t)1024 * HD * 2);
    __half* Wot    = (__half*)alloc((size_t)64 * HD * 2);
    float*  bc1    = (float*)alloc(1024 * 4);
    float*  bc2    = (float*)alloc(1024 * 4);
    int*    part   = (int*)alloc(512);            // scan partials (<=128 blocks)

    hipMemsetAsync(d_ws, 0, zbytes, stream);

    int total4x = N * (IN_DIM / 4);
    int prepWork = total4x > E ? total4x : E;
    if (prepWork < 411648) prepWork = 411648;
    prep_k<<<(prepWork + 255) / 256, 256, 0, stream>>>(
        (const float4*)x, xh, total4x, edst, counts, E,
        Wq1, Wk1, Wv1, Ws1, Wq2, Wk2, Wv2, Ws2, Wo,
        bq1, bk1, bv1, bs1, bq2, bk2, bv2, bs2,
        Wc1, Wc2, Wot, bc1, bc2);

    int nblkS = (N + 511) / 512;                  // 98 for N=50000 (<=128 req'd)
    scan_part_k<<<nblkS, 256, 0, stream>>>(counts, part, N);
    scan_fix_k<<<nblkS, 256, 0, stream>>>(counts, part, offs, cursor, N);
    scatter_k<<<(E / 2 + 255) / 256, 256, 0, stream>>>(esrc, edst, eattr, cursor,
                                                       edat, E);

    int nbx = (N + BM - 1) / BM;
    dim3 gqkvs(nbx * 8);                              // 1-D grid for XCD swizzle
    int nGroups = (N + 3) / 4;
    int gaBlocks = nGroups < 2048 ? nGroups : 2048;   // persistent blocks (proven R8 config)
    int total4 = N * (HD / 4);
    dim3 gl((total4 / 4 + 255) / 256);
    dim3 gout((N + 127) / 128);

    // ---- layer 1 ----
    gemm_mfma<<<gqkvs, 256, 0, stream>>>(xh, Wc1, bc1, qkvs, kv8, N, IN_DIM, 1024);
    attn_k<<<gaBlocks, 256, 0, stream>>>((const uint2*)qkvs, (const uint2*)kv8, We1,
                                         hwork, edat, offs, stats, N, nGroups);
    ln_apply<<<gl, 256, 0, stream>>>((const uint2*)hwork, hio,
                                     (const float4*)lnw1, (const float4*)lnb1,
                                     stats, (double)N * HD, total4);

    // ---- layer 2 ----
    gemm_mfma<<<gqkvs, 256, 0, stream>>>(hio, Wc2, bc2, qkvs, kv8, N, HD, 1024);
    attn_k<<<gaBlocks, 256, 0, stream>>>((const uint2*)qkvs, (const uint2*)kv8, We2,
                                         hwork, edat, offs, stats + 2, N, nGroups);
    ln_apply<<<gl, 256, 0, stream>>>((const uint2*)hwork, hio,
                                     (const float4*)lnw2, (const float4*)lnb2,
                                     stats + 2, (double)N * HD, total4);

    // ---- output projection (fp32 out, dedicated 128x64 kernel) ----
    gemm_out_k<<<gout, 256, 0, stream>>>(hio, Wot, bo, (float*)d_out, N);
}

// Round 16
// 513.504 us; speedup vs baseline: 1.0117x; 1.0038x over previous
//
#include <hip/hip_runtime.h>
#include <hip/hip_fp16.h>
#include <math.h>

#define IN_DIM 128
#define HD 256
#define EPSLN 1e-5f

typedef _Float16 half8 __attribute__((ext_vector_type(8)));
typedef float f32x4 __attribute__((ext_vector_type(4)));
typedef float f32x2 __attribute__((ext_vector_type(2)));

// ---------------- helpers ----------------
__device__ inline void store4(float* p, float4 o) { *(float4*)p = o; }
__device__ inline void store4(__half* p, float4 o) {
    union { uint2 u; __half2 h[2]; } s;
    s.h[0] = __floats2half2_rn(o.x, o.y);
    s.h[1] = __floats2half2_rn(o.z, o.w);
    *(uint2*)p = s.u;
}
__device__ inline float4 h4_to_f4(uint2 u) {
    union { unsigned int w; __half2 h; } a, b;
    a.w = u.x; b.w = u.y;
    float2 lo = __half22float2(a.h), hi = __half22float2(b.h);
    return make_float4(lo.x, lo.y, hi.x, hi.y);
}
// 4 floats -> 4 packed fp8 e4m3 (OCP, gfx950 HW cvt)
__device__ inline unsigned int f4_to_fp8x4(float a, float b, float c, float d) {
    int v = 0;
    v = __builtin_amdgcn_cvt_pk_fp8_f32(a, b, v, false);
    v = __builtin_amdgcn_cvt_pk_fp8_f32(c, d, v, true);
    return (unsigned int)v;
}
__device__ inline float4 fp8x4_to_f4(unsigned int u) {
    f32x2 lo = __builtin_amdgcn_cvt_pk_f32_fp8((int)u, false);
    f32x2 hi = __builtin_amdgcn_cvt_pk_f32_fp8((int)u, true);
    return make_float4(lo.x, lo.y, hi.x, hi.y);
}

__device__ inline void async_copy16(const __half* g, _Float16* l) {
    __builtin_amdgcn_global_load_lds(
        (const __attribute__((address_space(1))) void*)g,
        (__attribute__((address_space(3))) void*)l,
        16, 0, 0);
}

// Packed output column mapping: q[0:256) | kv-interleaved[256:768) | skip[768:1024)
__device__ inline void unpermute_col(int n, int& sel, int& c) {
    if (n < 256) { sel = 0; c = n; }
    else if (n < 768) {
        int j = n - 256, chunk = j >> 3, w = j & 7;
        if (w < 4) { sel = 1; c = chunk * 4 + w; }
        else       { sel = 2; c = chunk * 4 + w - 4; }
    } else { sel = 3; c = n - 768; }
}

// ---------------- fused prep: pack x, pack weights/biases, count degrees ----
// R20: counts atomic is FIRE-AND-FORGET (no return -> no per-wave dependency
// chain); slot claim moved to scatter_k's cursor atomic; rank array deleted.
__global__ void prep_k(
    const float4* __restrict__ x, __half* __restrict__ xh, int total4,
    const int* __restrict__ dst, int* __restrict__ counts, int E,
    const float* __restrict__ Wq1, const float* __restrict__ Wk1,
    const float* __restrict__ Wv1, const float* __restrict__ Ws1,
    const float* __restrict__ Wq2, const float* __restrict__ Wk2,
    const float* __restrict__ Wv2, const float* __restrict__ Ws2,
    const float* __restrict__ Wo,
    const float* __restrict__ bq1, const float* __restrict__ bk1,
    const float* __restrict__ bv1, const float* __restrict__ bs1,
    const float* __restrict__ bq2, const float* __restrict__ bk2,
    const float* __restrict__ bv2, const float* __restrict__ bs2,
    __half* __restrict__ Wc1, __half* __restrict__ Wc2, __half* __restrict__ Wot,
    float* __restrict__ bc1, float* __restrict__ bc2)
{
    int idx = blockIdx.x * 256 + threadIdx.x;
    if (idx < total4) store4(xh + (size_t)idx * 4, x[idx]);
    if (idx < E) atomicAdd(&counts[dst[idx]], 1);   // histogram only, no return
    if (idx < 131072) {
        int n = idx >> 7, k = idx & 127;
        int sel, c; unpermute_col(n, sel, c);
        const float* W = (sel == 0) ? Wq1 : (sel == 1) ? Wk1 : (sel == 2) ? Wv1 : Ws1;
        Wc1[idx] = __float2half(W[(size_t)k * 256 + c]);
    } else if (idx < 393216) {
        int j = idx - 131072;
        int n = j >> 8, k = j & 255;
        int sel, c; unpermute_col(n, sel, c);
        const float* W = (sel == 0) ? Wq2 : (sel == 1) ? Wk2 : (sel == 2) ? Wv2 : Ws2;
        Wc2[j] = __float2half(W[(size_t)k * 256 + c]);
    } else if (idx < 409600) {
        int j = idx - 393216;
        int n = j >> 8, k = j & 255;
        Wot[j] = __float2half(Wo[(size_t)k * 64 + n]);
    } else if (idx < 410624) {
        int n = idx - 409600;
        int sel, c; unpermute_col(n, sel, c);
        const float* b = (sel == 0) ? bq1 : (sel == 1) ? bk1 : (sel == 2) ? bv1 : bs1;
        bc1[n] = b[c];
    } else if (idx < 411648) {
        int n = idx - 410624;
        int sel, c; unpermute_col(n, sel, c);
        const float* b = (sel == 0) ? bq2 : (sel == 1) ? bk2 : (sel == 2) ? bv2 : bs2;
        bc2[n] = b[c];
    }
}

// ---------------- MFMA GEMM: C[M x Nc] = A[M x K] @ Wt^T + bias (f16 out) ----------------
// R13: 1-D grid + XCD-grouping swizzle (measured R4: ~44us win across both gemms).
// R17/R18: BK=32 single-barrier double-buffer (measured R11: neutral; kept as
// the verified config). LDS: As0@0, Bs0@8K, As1@16K, Bs1@24K within the
// 34,816B epilogue region. Buffer bases computed per-use (LDS pointer arrays
// fail to compile on gfx950 — R10 lesson).
#define BM 128
#define BN 128
#define TROWB 272   // f16 out-tile row stride (bytes)

__global__ __launch_bounds__(256) void gemm_mfma(
    const __half* __restrict__ A, const __half* __restrict__ Wt,
    const float* __restrict__ bias, __half* __restrict__ C,
    unsigned char* __restrict__ kv8,
    int M, int K, int Nc)
{
    __shared__ char smem[BM * TROWB];          // 34,816 B; dbuf overlaid below

    int tid = threadIdx.x;
    int lane = tid & 63, w = tid >> 6;
    int wm = w >> 1, wn = w & 1;
    int quad = lane >> 4, l16 = lane & 15;
    // XCD swizzle: nwg = nbx*8 (exact multiple of 8 XCDs)
    int nbx = (int)gridDim.x >> 3;
    int wkr = ((int)blockIdx.x & 7) * nbx + ((int)blockIdx.x >> 3);
    int row0 = (wkr >> 3) * BM;
    int col0 = (wkr & 7) * BN;

    f32x4 acc[4][4];
#pragma unroll
    for (int i = 0; i < 4; i++)
#pragma unroll
        for (int j = 0; j < 4; j++) acc[i][j] = (f32x4){0.f, 0.f, 0.f, 0.f};

    int srow = lane >> 2;      // 0..15 (16 rows per wave-instruction at BK=32)
    int schunk = lane & 3;     // 4 chunks of 8 f16 per 64B row

    int nt = K >> 5;           // K/32 steps

    // STAGE(step, buf): issue A+B tile loads for k0 = step*32 into buffer buf
    auto STAGE = [&](int step, int buf) {
        int k0 = step << 5;
        _Float16* Asb = (_Float16*)(smem + buf * 16384);
        _Float16* Bsb = (_Float16*)(smem + 8192 + buf * 16384);
#pragma unroll
        for (int t = 0; t < 2; t++) {
            int r = w * 32 + t * 16 + srow;
            int gr = row0 + r; if (gr > M - 1) gr = M - 1;
            int gchunk = schunk ^ ((r ^ (r >> 2)) & 3);
            async_copy16(&A[(size_t)gr * K + k0 + gchunk * 8], &Asb[(w * 32 + t * 16) * 32]);
        }
#pragma unroll
        for (int t = 0; t < 2; t++) {
            int r = w * 32 + t * 16 + srow;
            int gc = col0 + r; if (gc > Nc - 1) gc = Nc - 1;
            int gchunk = schunk ^ ((r ^ (r >> 2)) & 3);
            async_copy16(&Wt[(size_t)gc * K + k0 + gchunk * 8], &Bsb[(w * 32 + t * 16) * 32]);
        }
    };

    STAGE(0, 0);
    __syncthreads();

    for (int t = 0; t < nt; ++t) {
        if (t + 1 < nt) STAGE(t + 1, (t + 1) & 1);
        _Float16* Asb = (_Float16*)(smem + (t & 1) * 16384);
        _Float16* Bsb = (_Float16*)(smem + 8192 + (t & 1) * 16384);
        half8 af[4], bf[4];
#pragma unroll
        for (int i = 0; i < 4; i++) {
            int ra = wm * 64 + i * 16 + l16;
            af[i] = *(half8*)&Asb[ra * 32 + ((quad ^ ((ra ^ (ra >> 2)) & 3)) * 8)];
            int rb = wn * 64 + i * 16 + l16;
            bf[i] = *(half8*)&Bsb[rb * 32 + ((quad ^ ((rb ^ (rb >> 2)) & 3)) * 8)];
        }
#pragma unroll
        for (int i = 0; i < 4; i++)
#pragma unroll
            for (int j = 0; j < 4; j++)
                acc[i][j] = __builtin_amdgcn_mfma_f32_16x16x32_f16(af[i], bf[j], acc[i][j], 0, 0, 0);
        __syncthreads();
    }

#pragma unroll
    for (int j = 0; j < 4; j++) {
        int tcol = wn * 64 + j * 16 + l16;
        float bb = (col0 + tcol < Nc) ? bias[col0 + tcol] : 0.f;
#pragma unroll
        for (int i = 0; i < 4; i++) {
#pragma unroll
            for (int r = 0; r < 4; r++) {
                int trow = wm * 64 + i * 16 + quad * 4 + r;
                ((__half*)(smem + trow * TROWB))[tcol] = __float2half(acc[i][j][r] + bb);
            }
        }
    }
    __syncthreads();
    bool iskv = (col0 >= 256) && (col0 < 768);
    int crow = tid >> 4, cchunk = tid & 15;
    for (int p = 0; p < 8; p++) {
        int trow = p * 16 + crow;
        int grow = row0 + trow;
        if (grow >= M) continue;
        uint4 val = *(uint4*)(smem + trow * TROWB + cchunk * 16);
        if (iskv) {
            float4 lo = h4_to_f4(make_uint2(val.x, val.y));
            float4 hi = h4_to_f4(make_uint2(val.z, val.w));
            uint2 o8;
            o8.x = f4_to_fp8x4(lo.x, lo.y, lo.z, lo.w);
            o8.y = f4_to_fp8x4(hi.x, hi.y, hi.z, hi.w);
            *(uint2*)&kv8[(size_t)grow * 512 + (col0 - 256) + cchunk * 8] = o8;
        } else {
            *(uint4*)&C[(size_t)grow * Nc + col0 + cchunk * 8] = val;
        }
    }
}

// ---------------- output GEMM: D[M x 64] = A[M x 256] @ Wot^T + bo (fp32 out) ----------
// R17/R18: BK=32 single-barrier double-buffer. LDS 24KB.
// Layout (halfs): As0@0 (4096), As1@4096, Bs0@8192 (2048), Bs1@10240.
__global__ __launch_bounds__(256) void gemm_out_k(
    const __half* __restrict__ A, const __half* __restrict__ Wot,
    const float* __restrict__ bias, float* __restrict__ D, int M)
{
    __shared__ _Float16 smem[12288];   // 24 KB
    int tid = threadIdx.x;
    int lane = tid & 63, w = tid >> 6;
    int quad = lane >> 4, l16 = lane & 15;
    int row0 = blockIdx.x * 128;
    const int K = 256;

    f32x4 acc[2][4];
#pragma unroll
    for (int i = 0; i < 2; i++)
#pragma unroll
        for (int j = 0; j < 4; j++) acc[i][j] = (f32x4){0.f, 0.f, 0.f, 0.f};

    int srow = lane >> 2;
    int schunk = lane & 3;
    const int nt = 8;   // 256/32

    auto STAGE = [&](int step, int buf) {
        int k0 = step << 5;
        _Float16* Asb = smem + buf * 4096;
        _Float16* Bsb = smem + 8192 + buf * 2048;
#pragma unroll
        for (int t = 0; t < 2; t++) {
            int r = w * 32 + t * 16 + srow;
            int gr = row0 + r; if (gr > M - 1) gr = M - 1;
            int gchunk = schunk ^ ((r ^ (r >> 2)) & 3);
            async_copy16(&A[(size_t)gr * K + k0 + gchunk * 8], &Asb[(w * 32 + t * 16) * 32]);
        }
        {
            int r = w * 16 + srow;       // 64 weight rows, one wave-inst per wave
            int gchunk = schunk ^ ((r ^ (r >> 2)) & 3);
            async_copy16(&Wot[(size_t)r * K + k0 + gchunk * 8], &Bsb[(w * 16) * 32]);
        }
    };

    STAGE(0, 0);
    __syncthreads();

    for (int t = 0; t < nt; ++t) {
        if (t + 1 < nt) STAGE(t + 1, (t + 1) & 1);
        _Float16* Asb = smem + (t & 1) * 4096;
        _Float16* Bsb = smem + 8192 + (t & 1) * 2048;
        half8 af[2], bf[4];
#pragma unroll
        for (int i = 0; i < 2; i++) {
            int ra = w * 32 + i * 16 + l16;
            af[i] = *(half8*)&Asb[ra * 32 + ((quad ^ ((ra ^ (ra >> 2)) & 3)) * 8)];
        }
#pragma unroll
        for (int j = 0; j < 4; j++) {
            int rb = j * 16 + l16;
            bf[j] = *(half8*)&Bsb[rb * 32 + ((quad ^ ((rb ^ (rb >> 2)) & 3)) * 8)];
        }
#pragma unroll
        for (int i = 0; i < 2; i++)
#pragma unroll
            for (int j = 0; j < 4; j++)
                acc[i][j] = __builtin_amdgcn_mfma_f32_16x16x32_f16(af[i], bf[j], acc[i][j], 0, 0, 0);
        __syncthreads();
    }

#pragma unroll
    for (int i = 0; i < 2; i++) {
#pragma unroll
        for (int j = 0; j < 4; j++) {
            int gcol = j * 16 + l16;
            float bb = bias[gcol];
#pragma unroll
            for (int r = 0; r < 4; r++) {
                int grow = row0 + w * 32 + i * 16 + quad * 4 + r;
                if (grow < M) D[(size_t)grow * 64 + gcol] = acc[i][j][r] + bb;
            }
        }
    }
}

// ---------------- edge bucketing: 2-phase parallel scan (R19/R21) ----------------
__global__ __launch_bounds__(256) void scan_part_k(const int* __restrict__ counts,
                                                   int* __restrict__ part, int n)
{
    int b = blockIdx.x, t = threadIdx.x;
    int i0 = b * 512 + t * 2;
    int s = 0;
    if (i0 < n) s += counts[i0];
    if (i0 + 1 < n) s += counts[i0 + 1];
    int lane = t & 63, wid = t >> 6;
    int v = s;
#pragma unroll
    for (int d = 1; d < 64; d <<= 1) v += __shfl_xor(v, d);
    __shared__ int ws[4];
    if (lane == 0) ws[wid] = v;
    __syncthreads();
    if (t == 0) part[b] = ws[0] + ws[1] + ws[2] + ws[3];
}

// R20: emits cursor[] (copy of exclusive prefix) for scatter_k's slot-claims.
// R21: computes its own block base from raw part[] sums (top-scan fused,
// one fewer launch).
__global__ __launch_bounds__(256) void scan_fix_k(const int* __restrict__ counts,
                                                  const int* __restrict__ part,
                                                  int* __restrict__ offs,
                                                  int* __restrict__ cursor, int n)
{
    __shared__ int sbase[2];
    int b = blockIdx.x, t = threadIdx.x;
    int lane = t & 63, wid = t >> 6;
    // block base = sum of part[j] for j < b (b <= 127; threads 0-127 help)
    {
        int pv = (t < b) ? part[t] : 0;      // b<=127 so t<128 covers all
        int vv = pv;
#pragma unroll
        for (int d = 1; d < 64; d <<= 1) vv += __shfl_xor(vv, d);
        if (lane == 0 && wid < 2) sbase[wid] = vv;
        __syncthreads();
    }
    int base = sbase[0] + sbase[1];

    int i0 = b * 512 + t * 2;
    int c0 = (i0 < n) ? counts[i0] : 0;
    int c1 = (i0 + 1 < n) ? counts[i0 + 1] : 0;
    int s = c0 + c1;
    int v = s;
#pragma unroll
    for (int d = 1; d < 64; d <<= 1) {
        int u = __shfl_up(v, (unsigned)d, 64);
        if (lane >= d) v += u;
    }
    __shared__ int wsum[4], wpre[4];
    if (lane == 63) wsum[wid] = v;
    __syncthreads();
    if (t == 0) { int a = 0; for (int i = 0; i < 4; i++) { wpre[i] = a; a += wsum[i]; } }
    __syncthreads();
    int pre = base + wpre[wid] + v - s;   // exclusive prefix for this thread
    if (i0 < n) { offs[i0] = pre; cursor[i0] = pre; }
    if (i0 + 1 < n) { offs[i0 + 1] = pre + c0; cursor[i0 + 1] = pre + c0; }
    int end = i0 + 2; if (end > n) end = n;
    if (end == n) offs[n] = pre + c0 + c1;   // racing writers all write the total
}

// R20: slot claim via cursor atomic. R22: REVERTED R21's 2-edge packing —
// scatter is atomic-latency-bound (returning atomicAdd ~300-900cy); packing
// 2 edges/thread halved TLP and doubled the per-thread serial chain
// (measured R15: non-attn +30us canary-normalized). 1 edge/thread, max TLP.
// Pads 8 entries past the end so attn tail batches can overrun safely.
__global__ void scatter_k(const int* __restrict__ src, const int* __restrict__ dst,
                          const float* __restrict__ attr, int* __restrict__ cursor,
                          int2* __restrict__ edat, int E)
{
    int e = blockIdx.x * 256 + threadIdx.x;
    if (e < 8) edat[E + e] = make_int2(0, 0);
    if (e < E) {
        int p = atomicAdd(&cursor[dst[e]], 1);
        edat[p] = make_int2(src[e], __float_as_int(attr[e]));
    }
}

// ---------------- attention: one wave per dst node, batched online softmax ----
// R9-MEASURED VERSION, EXACT SOURCE (100.5us fast-container, VGPR=64, SGPR=80,
// occ 34%). DO NOT REPHRASE THIS LOOP (R7: +8 VGPR -> -9%).
// HARD CONSTRAINT (R5/R6/R7): VGPR <= 64 — TLP-limited at the 8-waves/SIMD max.
// This kernel is the cross-run clock canary: normalize totals by its dur.
__global__ __launch_bounds__(256) void attn_k(
    const uint2* __restrict__ q2, const uint2* __restrict__ kv8u2,
    const float* __restrict__ We,
    __half* __restrict__ hwork, const int2* __restrict__ edat,
    const int* __restrict__ offs,
    double* __restrict__ stats, int n, int nGroups)
{
    int lane = threadIdx.x & 63;
    int wid = threadIdx.x >> 6;
    float4 we = ((const float4*)We)[lane];
    float tsum = 0.f, tsq = 0.f;

    for (int g = blockIdx.x; g < nGroups; g += gridDim.x) {
        int node = g * 4 + wid;
        if (node >= n) continue;
        float4 qv = h4_to_f4(q2[(size_t)node * 256 + lane]);
        float qwe = qv.x * we.x + qv.y * we.y + qv.z * we.z + qv.w * we.w;
        qwe += __shfl_xor(qwe, 1);
        qwe += __shfl_xor(qwe, 2);
        qwe += __shfl_xor(qwe, 4);

        float4 accv = make_float4(0.f, 0.f, 0.f, 0.f);
        float sat = 0.f;
        float m = -INFINITY, l = 0.f;
        int i0 = __builtin_amdgcn_readfirstlane(offs[node]);
        int i1 = __builtin_amdgcn_readfirstlane(offs[node + 1]);

        int abA[8], srA[8], abB[8], srB[8];   // SGPR: attr bits / src index
        uint2 kvA[8], kvB[8];

        auto LOADB = [&](int base, int* ab_, int* sr_, uint2* kv_) {
#pragma unroll
            for (int u = 0; u < 8; u++) {
                int2 ed = edat[base + u];                     // uniform addr
                sr_[u] = __builtin_amdgcn_readfirstlane(ed.x);
                ab_[u] = __builtin_amdgcn_readfirstlane(ed.y);
            }
#pragma unroll
            for (int u = 0; u < 8; u++)
                kv_[u] = (kv8u2 + (size_t)(unsigned)sr_[u] * 64)[lane];
        };

        auto COMPUTE = [&](const int* ab_, const uint2* kv_, int cnt) {
            float pv[8];
#pragma unroll
            for (int u = 0; u < 8; u++) {
                float4 kvf = fp8x4_to_f4(kv_[u].x);
                float p = qv.x * kvf.x + qv.y * kvf.y + qv.z * kvf.z + qv.w * kvf.w;
                p += __shfl_xor(p, 1);
                p += __shfl_xor(p, 2);
                p += __shfl_xor(p, 4);
                p = fmaf(__int_as_float(ab_[u]), qwe, p) * 0.17677669529663687f;
                pv[u] = (u < cnt) ? p : -INFINITY;            // folds away for cnt=8
            }
            float m01 = fmaxf(pv[0], pv[1]), m23 = fmaxf(pv[2], pv[3]);
            float m45 = fmaxf(pv[4], pv[5]), m67 = fmaxf(pv[6], pv[7]);
            float pmax = fmaxf(fmaxf(m01, m23), fmaxf(m45, m67));
            float mn = fmaxf(m, pmax);
            float corr = __expf(m - mn);
            l *= corr;
            sat *= corr;
            accv.x *= corr; accv.y *= corr; accv.z *= corr; accv.w *= corr;
#pragma unroll
            for (int u = 0; u < 8; u++) {
                float wgt = __expf(pv[u] - mn);               // pad: exp(-inf)=0
                l += wgt;
                sat = fmaf(wgt, __int_as_float(ab_[u]), sat);
                float4 vv = fp8x4_to_f4(kv_[u].y);
                accv.x = fmaf(wgt, vv.x, accv.x);
                accv.y = fmaf(wgt, vv.y, accv.y);
                accv.z = fmaf(wgt, vv.z, accv.z);
                accv.w = fmaf(wgt, vv.w, accv.w);
            }
            m = mn;
        };

        if (i0 < i1) {
            int i = i0;
            LOADB(i, abA, srA, kvA);
            while (true) {
                if (i + 8 >= i1) { COMPUTE(abA, kvA, i1 - i); break; }
                LOADB(i + 8, abB, srB, kvB);
                COMPUTE(abA, kvA, 8);
                i += 8;
                if (i + 8 >= i1) { COMPUTE(abB, kvB, i1 - i); break; }
                LOADB(i + 8, abA, srA, kvA);
                COMPUTE(abB, kvB, 8);
                i += 8;
            }
        }

        float inv = (l > 0.f) ? 1.f / l : 0.f;
        float4 sk = h4_to_f4(q2[(size_t)node * 256 + 192 + lane]);
        float sw = sat * inv;
        float4 o;
        o.x = fmaf(accv.x, inv, fmaf(sw, we.x, sk.x));
        o.y = fmaf(accv.y, inv, fmaf(sw, we.y, sk.y));
        o.z = fmaf(accv.z, inv, fmaf(sw, we.z, sk.z));
        o.w = fmaf(accv.w, inv, fmaf(sw, we.w, sk.w));
        store4(hwork + (size_t)node * 256 + lane * 4, o);
        tsum += o.x + o.y + o.z + o.w;
        tsq += o.x * o.x + o.y * o.y + o.z * o.z + o.w * o.w;
    }

#pragma unroll
    for (int d = 1; d < 64; d <<= 1) {
        tsum += __shfl_xor(tsum, d);
        tsq += __shfl_xor(tsq, d);
    }
    __shared__ float red[8];
    if (lane == 0) { red[wid] = tsum; red[4 + wid] = tsq; }
    __syncthreads();
    if (threadIdx.x == 0) {
        double s = (double)red[0] + (double)red[1] + (double)red[2] + (double)red[3];
        double sq = (double)red[4] + (double)red[5] + (double)red[6] + (double)red[7];
        atomicAdd(&stats[0], s);
        atomicAdd(&stats[1], sq);
    }
}

// ---------------- LayerNorm apply (R19: per-block stats, 16B vector IO) ----------------
__global__ __launch_bounds__(256) void ln_apply(
    const uint2* __restrict__ in, __half* __restrict__ out,
    const float4* __restrict__ w4, const float4* __restrict__ b4,
    const double* __restrict__ stats, double cnt, int total4)
{
    __shared__ float sm[2];
    if (threadIdx.x == 0) {
        double mu = stats[0] / cnt;
        double var = stats[1] / cnt - mu * mu;
        if (var < 0.0) var = 0.0;
        sm[0] = (float)mu;
        sm[1] = (float)(1.0 / (sqrt(var) + (double)EPSLN));
    }
    __syncthreads();
    int base = (blockIdx.x * 256 + threadIdx.x) * 4;
    if (base >= total4) return;
    float mean = sm[0];
    float inv = sm[1];

    uint4 ra = *(const uint4*)(in + base);        // i = base, base+1
    uint4 rb = *(const uint4*)(in + base + 2);    // i = base+2, base+3
    uint2 rw[4] = { make_uint2(ra.x, ra.y), make_uint2(ra.z, ra.w),
                    make_uint2(rb.x, rb.y), make_uint2(rb.z, rb.w) };
    uint2 ow[4];
#pragma unroll
    for (int u = 0; u < 4; u++) {
        int i = base + u;
        int c = i & 63;
        float4 xv = h4_to_f4(rw[u]);
        float4 w = w4[c], b = b4[c];
        float4 o;
        o.x = fmaf((xv.x - mean) * inv, w.x, b.x);
        o.y = fmaf((xv.y - mean) * inv, w.y, b.y);
        o.z = fmaf((xv.z - mean) * inv, w.z, b.z);
        o.w = fmaf((xv.w - mean) * inv, w.w, b.w);
        o.x = o.x > 0.f ? o.x : expm1f(o.x);
        o.y = o.y > 0.f ? o.y : expm1f(o.y);
        o.z = o.z > 0.f ? o.z : expm1f(o.z);
        o.w = o.w > 0.f ? o.w : expm1f(o.w);
        union { uint2 u2; __half2 h[2]; } s;
        s.h[0] = __floats2half2_rn(o.x, o.y);
        s.h[1] = __floats2half2_rn(o.z, o.w);
        ow[u] = s.u2;
    }
    uint4 s0 = make_uint4(ow[0].x, ow[0].y, ow[1].x, ow[1].y);
    uint4 s1 = make_uint4(ow[2].x, ow[2].y, ow[3].x, ow[3].y);
    *(uint4*)(out + (size_t)base * 4) = s0;
    *(uint4*)(out + (size_t)(base + 2) * 4) = s1;
}

// ---------------- driver ----------------
extern "C" void kernel_launch(void* const* d_in, const int* in_sizes, int n_in,
                              void* d_out, int out_size, void* d_ws, size_t ws_size,
                              hipStream_t stream)
{
    const float* x      = (const float*)d_in[0];
    const int*   ei     = (const int*)d_in[1];
    const float* eattr  = (const float*)d_in[2];
    const float* Wq1 = (const float*)d_in[3];  const float* bq1 = (const float*)d_in[4];
    const float* Wk1 = (const float*)d_in[5];  const float* bk1 = (const float*)d_in[6];
    const float* Wv1 = (const float*)d_in[7];  const float* bv1 = (const float*)d_in[8];
    const float* We1 = (const float*)d_in[9];
    const float* Ws1 = (const float*)d_in[10]; const float* bs1 = (const float*)d_in[11];
    const float* lnw1 = (const float*)d_in[12]; const float* lnb1 = (const float*)d_in[13];
    const float* Wq2 = (const float*)d_in[14]; const float* bq2 = (const float*)d_in[15];
    const float* Wk2 = (const float*)d_in[16]; const float* bk2 = (const float*)d_in[17];
    const float* Wv2 = (const float*)d_in[18]; const float* bv2 = (const float*)d_in[19];
    const float* We2 = (const float*)d_in[20];
    const float* Ws2 = (const float*)d_in[21]; const float* bs2 = (const float*)d_in[22];
    const float* lnw2 = (const float*)d_in[23]; const float* lnb2 = (const float*)d_in[24];
    const float* Wo  = (const float*)d_in[25]; const float* bo  = (const float*)d_in[26];

    const int N = in_sizes[0] / IN_DIM;
    const int E = in_sizes[2];
    const int* esrc = ei;
    const int* edst = ei + E;

    char* ws = (char*)d_ws;
    size_t off = 0;
    auto alloc = [&](size_t bytes) -> char* {
        char* p = ws + off;
        off += (bytes + 255) / 256 * 256;
        return p;
    };
    int*    counts = (int*)alloc((size_t)N * 4);
    double* stats  = (double*)alloc(64);
    size_t zbytes = off;
    int*    cursor = (int*)alloc((size_t)N * 4);
    int*    offs   = (int*)alloc((size_t)(N + 1) * 4);
    int2*   edat   = (int2*)alloc((size_t)(E + 8) * 8);
    __half* xh     = (__half*)alloc((size_t)N * IN_DIM * 2);
    __half* qkvs   = (__half*)alloc((size_t)N * 1024 * 2);
    unsigned char* kv8 = (unsigned char*)alloc((size_t)N * 512);
    __half* hwork  = (__half*)alloc((size_t)N * HD * 2);
    __half* hio    = (__half*)alloc((size_t)N * HD * 2);
    __half* Wc1    = (__half*)alloc((size_t)1024 * IN_DIM * 2);
    __half* Wc2    = (__half*)alloc((size_t)1024 * HD * 2);
    __half* Wot    = (__half*)alloc((size_t)64 * HD * 2);
    float*  bc1    = (float*)alloc(1024 * 4);
    float*  bc2    = (float*)alloc(1024 * 4);
    int*    part   = (int*)alloc(512);            // scan partials (<=128 blocks)

    hipMemsetAsync(d_ws, 0, zbytes, stream);

    int total4x = N * (IN_DIM / 4);
    int prepWork = total4x > E ? total4x : E;
    if (prepWork < 411648) prepWork = 411648;
    prep_k<<<(prepWork + 255) / 256, 256, 0, stream>>>(
        (const float4*)x, xh, total4x, edst, counts, E,
        Wq1, Wk1, Wv1, Ws1, Wq2, Wk2, Wv2, Ws2, Wo,
        bq1, bk1, bv1, bs1, bq2, bk2, bv2, bs2,
        Wc1, Wc2, Wot, bc1, bc2);

    int nblkS = (N + 511) / 512;                  // 98 for N=50000 (<=128 req'd)
    scan_part_k<<<nblkS, 256, 0, stream>>>(counts, part, N);
    scan_fix_k<<<nblkS, 256, 0, stream>>>(counts, part, offs, cursor, N);
    scatter_k<<<(E + 255) / 256, 256, 0, stream>>>(esrc, edst, eattr, cursor,
                                                   edat, E);

    int nbx = (N + BM - 1) / BM;
    dim3 gqkvs(nbx * 8);                              // 1-D grid for XCD swizzle
    int nGroups = (N + 3) / 4;
    int gaBlocks = nGroups < 2048 ? nGroups : 2048;   // persistent blocks (proven R8 config)
    int total4 = N * (HD / 4);
    dim3 gl((total4 / 4 + 255) / 256);
    dim3 gout((N + 127) / 128);

    // ---- layer 1 ----
    gemm_mfma<<<gqkvs, 256, 0, stream>>>(xh, Wc1, bc1, qkvs, kv8, N, IN_DIM, 1024);
    attn_k<<<gaBlocks, 256, 0, stream>>>((const uint2*)qkvs, (const uint2*)kv8, We1,
                                         hwork, edat, offs, stats, N, nGroups);
    ln_apply<<<gl, 256, 0, stream>>>((const uint2*)hwork, hio,
                                     (const float4*)lnw1, (const float4*)lnb1,
                                     stats, (double)N * HD, total4);

    // ---- layer 2 ----
    gemm_mfma<<<gqkvs, 256, 0, stream>>>(hio, Wc2, bc2, qkvs, kv8, N, HD, 1024);
    attn_k<<<gaBlocks, 256, 0, stream>>>((const uint2*)qkvs, (const uint2*)kv8, We2,
                                         hwork, edat, offs, stats + 2, N, nGroups);
    ln_apply<<<gl, 256, 0, stream>>>((const uint2*)hwork, hio,
                                     (const float4*)lnw2, (const float4*)lnb2,
                                     stats + 2, (double)N * HD, total4);

    // ---- output projection (fp32 out, dedicated 128x64 kernel) ----
    gemm_out_k<<<gout, 256, 0, stream>>>(hio, Wot, bo, (float*)d_out, N);
}

// Round 17
// 498.359 us; speedup vs baseline: 1.0424x; 1.0304x over previous
//
#include <hip/hip_runtime.h>
#include <hip/hip_fp16.h>
#include <math.h>

#define IN_DIM 128
#define HD 256
#define EPSLN 1e-5f

typedef _Float16 half8 __attribute__((ext_vector_type(8)));
typedef float f32x4 __attribute__((ext_vector_type(4)));
typedef float f32x2 __attribute__((ext_vector_type(2)));

// ---------------- helpers ----------------
__device__ inline void store4(float* p, float4 o) { *(float4*)p = o; }
__device__ inline void store4(__half* p, float4 o) {
    union { uint2 u; __half2 h[2]; } s;
    s.h[0] = __floats2half2_rn(o.x, o.y);
    s.h[1] = __floats2half2_rn(o.z, o.w);
    *(uint2*)p = s.u;
}
__device__ inline float4 h4_to_f4(uint2 u) {
    union { unsigned int w; __half2 h; } a, b;
    a.w = u.x; b.w = u.y;
    float2 lo = __half22float2(a.h), hi = __half22float2(b.h);
    return make_float4(lo.x, lo.y, hi.x, hi.y);
}
// 4 floats -> 4 packed fp8 e4m3 (OCP, gfx950 HW cvt)
__device__ inline unsigned int f4_to_fp8x4(float a, float b, float c, float d) {
    int v = 0;
    v = __builtin_amdgcn_cvt_pk_fp8_f32(a, b, v, false);
    v = __builtin_amdgcn_cvt_pk_fp8_f32(c, d, v, true);
    return (unsigned int)v;
}
__device__ inline float4 fp8x4_to_f4(unsigned int u) {
    f32x2 lo = __builtin_amdgcn_cvt_pk_f32_fp8((int)u, false);
    f32x2 hi = __builtin_amdgcn_cvt_pk_f32_fp8((int)u, true);
    return make_float4(lo.x, lo.y, hi.x, hi.y);
}

__device__ inline void async_copy16(const __half* g, _Float16* l) {
    __builtin_amdgcn_global_load_lds(
        (const __attribute__((address_space(1))) void*)g,
        (__attribute__((address_space(3))) void*)l,
        16, 0, 0);
}

// Packed output column mapping: q[0:256) | kv-interleaved[256:768) | skip[768:1024)
__device__ inline void unpermute_col(int n, int& sel, int& c) {
    if (n < 256) { sel = 0; c = n; }
    else if (n < 768) {
        int j = n - 256, chunk = j >> 3, w = j & 7;
        if (w < 4) { sel = 1; c = chunk * 4 + w; }
        else       { sel = 2; c = chunk * 4 + w - 4; }
    } else { sel = 3; c = n - 768; }
}

// ---------------- fused prep: pack x, pack weights/biases, count degrees + ranks ----
// R23: REVERTED to the R12-measured-best rank scheme. The R20 cursor move was
// a false win from mis-normalized cross-container clocks: the returning
// atomicAdd hidden under prep's 411K-thread weight-pack work costs ~nothing,
// but the same atomic as a dedicated scatter critical path cost ~20us.
__global__ void prep_k(
    const float4* __restrict__ x, __half* __restrict__ xh, int total4,
    const int* __restrict__ dst, int* __restrict__ counts, int* __restrict__ rank, int E,
    const float* __restrict__ Wq1, const float* __restrict__ Wk1,
    const float* __restrict__ Wv1, const float* __restrict__ Ws1,
    const float* __restrict__ Wq2, const float* __restrict__ Wk2,
    const float* __restrict__ Wv2, const float* __restrict__ Ws2,
    const float* __restrict__ Wo,
    const float* __restrict__ bq1, const float* __restrict__ bk1,
    const float* __restrict__ bv1, const float* __restrict__ bs1,
    const float* __restrict__ bq2, const float* __restrict__ bk2,
    const float* __restrict__ bv2, const float* __restrict__ bs2,
    __half* __restrict__ Wc1, __half* __restrict__ Wc2, __half* __restrict__ Wot,
    float* __restrict__ bc1, float* __restrict__ bc2)
{
    int idx = blockIdx.x * 256 + threadIdx.x;
    if (idx < total4) store4(xh + (size_t)idx * 4, x[idx]);
    if (idx < E) rank[idx] = atomicAdd(&counts[dst[idx]], 1);   // rank within dst bucket
    if (idx < 131072) {
        int n = idx >> 7, k = idx & 127;
        int sel, c; unpermute_col(n, sel, c);
        const float* W = (sel == 0) ? Wq1 : (sel == 1) ? Wk1 : (sel == 2) ? Wv1 : Ws1;
        Wc1[idx] = __float2half(W[(size_t)k * 256 + c]);
    } else if (idx < 393216) {
        int j = idx - 131072;
        int n = j >> 8, k = j & 255;
        int sel, c; unpermute_col(n, sel, c);
        const float* W = (sel == 0) ? Wq2 : (sel == 1) ? Wk2 : (sel == 2) ? Wv2 : Ws2;
        Wc2[j] = __float2half(W[(size_t)k * 256 + c]);
    } else if (idx < 409600) {
        int j = idx - 393216;
        int n = j >> 8, k = j & 255;
        Wot[j] = __float2half(Wo[(size_t)k * 64 + n]);
    } else if (idx < 410624) {
        int n = idx - 409600;
        int sel, c; unpermute_col(n, sel, c);
        const float* b = (sel == 0) ? bq1 : (sel == 1) ? bk1 : (sel == 2) ? bv1 : bs1;
        bc1[n] = b[c];
    } else if (idx < 411648) {
        int n = idx - 410624;
        int sel, c; unpermute_col(n, sel, c);
        const float* b = (sel == 0) ? bq2 : (sel == 1) ? bk2 : (sel == 2) ? bv2 : bs2;
        bc2[n] = b[c];
    }
}

// ---------------- MFMA GEMM: C[M x Nc] = A[M x K] @ Wt^T + bias (f16 out) ----------------
// R13: 1-D grid + XCD-grouping swizzle (measured R4: ~44us win across both gemms).
// R17/R18: BK=32 single-barrier double-buffer (measured R11: neutral; kept as
// the verified config). LDS: As0@0, Bs0@8K, As1@16K, Bs1@24K within the
// 34,816B epilogue region. Buffer bases computed per-use (LDS pointer arrays
// fail to compile on gfx950 — R10 lesson).
#define BM 128
#define BN 128
#define TROWB 272   // f16 out-tile row stride (bytes)

__global__ __launch_bounds__(256) void gemm_mfma(
    const __half* __restrict__ A, const __half* __restrict__ Wt,
    const float* __restrict__ bias, __half* __restrict__ C,
    unsigned char* __restrict__ kv8,
    int M, int K, int Nc)
{
    __shared__ char smem[BM * TROWB];          // 34,816 B; dbuf overlaid below

    int tid = threadIdx.x;
    int lane = tid & 63, w = tid >> 6;
    int wm = w >> 1, wn = w & 1;
    int quad = lane >> 4, l16 = lane & 15;
    // XCD swizzle: nwg = nbx*8 (exact multiple of 8 XCDs)
    int nbx = (int)gridDim.x >> 3;
    int wkr = ((int)blockIdx.x & 7) * nbx + ((int)blockIdx.x >> 3);
    int row0 = (wkr >> 3) * BM;
    int col0 = (wkr & 7) * BN;

    f32x4 acc[4][4];
#pragma unroll
    for (int i = 0; i < 4; i++)
#pragma unroll
        for (int j = 0; j < 4; j++) acc[i][j] = (f32x4){0.f, 0.f, 0.f, 0.f};

    int srow = lane >> 2;      // 0..15 (16 rows per wave-instruction at BK=32)
    int schunk = lane & 3;     // 4 chunks of 8 f16 per 64B row

    int nt = K >> 5;           // K/32 steps

    // STAGE(step, buf): issue A+B tile loads for k0 = step*32 into buffer buf
    auto STAGE = [&](int step, int buf) {
        int k0 = step << 5;
        _Float16* Asb = (_Float16*)(smem + buf * 16384);
        _Float16* Bsb = (_Float16*)(smem + 8192 + buf * 16384);
#pragma unroll
        for (int t = 0; t < 2; t++) {
            int r = w * 32 + t * 16 + srow;
            int gr = row0 + r; if (gr > M - 1) gr = M - 1;
            int gchunk = schunk ^ ((r ^ (r >> 2)) & 3);
            async_copy16(&A[(size_t)gr * K + k0 + gchunk * 8], &Asb[(w * 32 + t * 16) * 32]);
        }
#pragma unroll
        for (int t = 0; t < 2; t++) {
            int r = w * 32 + t * 16 + srow;
            int gc = col0 + r; if (gc > Nc - 1) gc = Nc - 1;
            int gchunk = schunk ^ ((r ^ (r >> 2)) & 3);
            async_copy16(&Wt[(size_t)gc * K + k0 + gchunk * 8], &Bsb[(w * 32 + t * 16) * 32]);
        }
    };

    STAGE(0, 0);
    __syncthreads();

    for (int t = 0; t < nt; ++t) {
        if (t + 1 < nt) STAGE(t + 1, (t + 1) & 1);
        _Float16* Asb = (_Float16*)(smem + (t & 1) * 16384);
        _Float16* Bsb = (_Float16*)(smem + 8192 + (t & 1) * 16384);
        half8 af[4], bf[4];
#pragma unroll
        for (int i = 0; i < 4; i++) {
            int ra = wm * 64 + i * 16 + l16;
            af[i] = *(half8*)&Asb[ra * 32 + ((quad ^ ((ra ^ (ra >> 2)) & 3)) * 8)];
            int rb = wn * 64 + i * 16 + l16;
            bf[i] = *(half8*)&Bsb[rb * 32 + ((quad ^ ((rb ^ (rb >> 2)) & 3)) * 8)];
        }
#pragma unroll
        for (int i = 0; i < 4; i++)
#pragma unroll
            for (int j = 0; j < 4; j++)
                acc[i][j] = __builtin_amdgcn_mfma_f32_16x16x32_f16(af[i], bf[j], acc[i][j], 0, 0, 0);
        __syncthreads();
    }

#pragma unroll
    for (int j = 0; j < 4; j++) {
        int tcol = wn * 64 + j * 16 + l16;
        float bb = (col0 + tcol < Nc) ? bias[col0 + tcol] : 0.f;
#pragma unroll
        for (int i = 0; i < 4; i++) {
#pragma unroll
            for (int r = 0; r < 4; r++) {
                int trow = wm * 64 + i * 16 + quad * 4 + r;
                ((__half*)(smem + trow * TROWB))[tcol] = __float2half(acc[i][j][r] + bb);
            }
        }
    }
    __syncthreads();
    bool iskv = (col0 >= 256) && (col0 < 768);
    int crow = tid >> 4, cchunk = tid & 15;
    for (int p = 0; p < 8; p++) {
        int trow = p * 16 + crow;
        int grow = row0 + trow;
        if (grow >= M) continue;
        uint4 val = *(uint4*)(smem + trow * TROWB + cchunk * 16);
        if (iskv) {
            float4 lo = h4_to_f4(make_uint2(val.x, val.y));
            float4 hi = h4_to_f4(make_uint2(val.z, val.w));
            uint2 o8;
            o8.x = f4_to_fp8x4(lo.x, lo.y, lo.z, lo.w);
            o8.y = f4_to_fp8x4(hi.x, hi.y, hi.z, hi.w);
            *(uint2*)&kv8[(size_t)grow * 512 + (col0 - 256) + cchunk * 8] = o8;
        } else {
            *(uint4*)&C[(size_t)grow * Nc + col0 + cchunk * 8] = val;
        }
    }
}

// ---------------- output GEMM: D[M x 64] = A[M x 256] @ Wot^T + bo (fp32 out) ----------
// R17/R18: BK=32 single-barrier double-buffer. LDS 24KB.
// Layout (halfs): As0@0 (4096), As1@4096, Bs0@8192 (2048), Bs1@10240.
__global__ __launch_bounds__(256) void gemm_out_k(
    const __half* __restrict__ A, const __half* __restrict__ Wot,
    const float* __restrict__ bias, float* __restrict__ D, int M)
{
    __shared__ _Float16 smem[12288];   // 24 KB
    int tid = threadIdx.x;
    int lane = tid & 63, w = tid >> 6;
    int quad = lane >> 4, l16 = lane & 15;
    int row0 = blockIdx.x * 128;
    const int K = 256;

    f32x4 acc[2][4];
#pragma unroll
    for (int i = 0; i < 2; i++)
#pragma unroll
        for (int j = 0; j < 4; j++) acc[i][j] = (f32x4){0.f, 0.f, 0.f, 0.f};

    int srow = lane >> 2;
    int schunk = lane & 3;
    const int nt = 8;   // 256/32

    auto STAGE = [&](int step, int buf) {
        int k0 = step << 5;
        _Float16* Asb = smem + buf * 4096;
        _Float16* Bsb = smem + 8192 + buf * 2048;
#pragma unroll
        for (int t = 0; t < 2; t++) {
            int r = w * 32 + t * 16 + srow;
            int gr = row0 + r; if (gr > M - 1) gr = M - 1;
            int gchunk = schunk ^ ((r ^ (r >> 2)) & 3);
            async_copy16(&A[(size_t)gr * K + k0 + gchunk * 8], &Asb[(w * 32 + t * 16) * 32]);
        }
        {
            int r = w * 16 + srow;       // 64 weight rows, one wave-inst per wave
            int gchunk = schunk ^ ((r ^ (r >> 2)) & 3);
            async_copy16(&Wot[(size_t)r * K + k0 + gchunk * 8], &Bsb[(w * 16) * 32]);
        }
    };

    STAGE(0, 0);
    __syncthreads();

    for (int t = 0; t < nt; ++t) {
        if (t + 1 < nt) STAGE(t + 1, (t + 1) & 1);
        _Float16* Asb = smem + (t & 1) * 4096;
        _Float16* Bsb = smem + 8192 + (t & 1) * 2048;
        half8 af[2], bf[4];
#pragma unroll
        for (int i = 0; i < 2; i++) {
            int ra = w * 32 + i * 16 + l16;
            af[i] = *(half8*)&Asb[ra * 32 + ((quad ^ ((ra ^ (ra >> 2)) & 3)) * 8)];
        }
#pragma unroll
        for (int j = 0; j < 4; j++) {
            int rb = j * 16 + l16;
            bf[j] = *(half8*)&Bsb[rb * 32 + ((quad ^ ((rb ^ (rb >> 2)) & 3)) * 8)];
        }
#pragma unroll
        for (int i = 0; i < 2; i++)
#pragma unroll
            for (int j = 0; j < 4; j++)
                acc[i][j] = __builtin_amdgcn_mfma_f32_16x16x32_f16(af[i], bf[j], acc[i][j], 0, 0, 0);
        __syncthreads();
    }

#pragma unroll
    for (int i = 0; i < 2; i++) {
#pragma unroll
        for (int j = 0; j < 4; j++) {
            int gcol = j * 16 + l16;
            float bb = bias[gcol];
#pragma unroll
            for (int r = 0; r < 4; r++) {
                int grow = row0 + w * 32 + i * 16 + quad * 4 + r;
                if (grow < M) D[(size_t)grow * 64 + gcol] = acc[i][j][r] + bb;
            }
        }
    }
}

// ---------------- edge bucketing: 3-phase parallel scan (R19, measured best) ----------
__global__ __launch_bounds__(256) void scan_part_k(const int* __restrict__ counts,
                                                   int* __restrict__ part, int n)
{
    int b = blockIdx.x, t = threadIdx.x;
    int i0 = b * 512 + t * 2;
    int s = 0;
    if (i0 < n) s += counts[i0];
    if (i0 + 1 < n) s += counts[i0 + 1];
    int lane = t & 63, wid = t >> 6;
    int v = s;
#pragma unroll
    for (int d = 1; d < 64; d <<= 1) v += __shfl_xor(v, d);
    __shared__ int ws[4];
    if (lane == 0) ws[wid] = v;
    __syncthreads();
    if (t == 0) part[b] = ws[0] + ws[1] + ws[2] + ws[3];
}

__global__ __launch_bounds__(128) void scan_top_k(int* __restrict__ part, int nb)
{
    // exclusive prefix over nb (<=128) entries, in place
    int t = threadIdx.x, lane = t & 63, wid = t >> 6;
    int orig = (t < nb) ? part[t] : 0;
    int v = orig;
#pragma unroll
    for (int d = 1; d < 64; d <<= 1) {
        int u = __shfl_up(v, (unsigned)d, 64);
        if (lane >= d) v += u;
    }
    __shared__ int wsum[2];
    if (lane == 63) wsum[wid] = v;
    __syncthreads();
    int add = (wid == 1) ? wsum[0] : 0;
    if (t < nb) part[t] = v + add - orig;   // exclusive base
}

__global__ __launch_bounds__(256) void scan_fix_k(const int* __restrict__ counts,
                                                  const int* __restrict__ part,
                                                  int* __restrict__ offs, int n)
{
    int b = blockIdx.x, t = threadIdx.x;
    int lane = t & 63, wid = t >> 6;
    int i0 = b * 512 + t * 2;
    int c0 = (i0 < n) ? counts[i0] : 0;
    int c1 = (i0 + 1 < n) ? counts[i0 + 1] : 0;
    int s = c0 + c1;
    int v = s;
#pragma unroll
    for (int d = 1; d < 64; d <<= 1) {
        int u = __shfl_up(v, (unsigned)d, 64);
        if (lane >= d) v += u;
    }
    __shared__ int wsum[4], wpre[4];
    if (lane == 63) wsum[wid] = v;
    __syncthreads();
    if (t == 0) { int a = 0; for (int i = 0; i < 4; i++) { wpre[i] = a; a += wsum[i]; } }
    __syncthreads();
    int pre = part[b] + wpre[wid] + v - s;   // exclusive prefix for this thread
    if (i0 < n) offs[i0] = pre;
    if (i0 + 1 < n) offs[i0 + 1] = pre + c0;
    int end = i0 + 2; if (end > n) end = n;
    if (end == n) offs[n] = pre + c0 + c1;   // racing writers all write the total
}

// atomic-free: position = segment offset + precomputed rank (R12-measured best).
// Pads 8 entries past the end so attn tail batches can overrun safely.
__global__ void scatter_k(const int* __restrict__ src, const int* __restrict__ dst,
                          const float* __restrict__ attr, const int* __restrict__ offs,
                          const int* __restrict__ rank, int2* __restrict__ edat, int E)
{
    int e = blockIdx.x * 256 + threadIdx.x;
    if (e < 8) edat[E + e] = make_int2(0, 0);
    if (e < E) {
        int p = offs[dst[e]] + rank[e];
        edat[p] = make_int2(src[e], __float_as_int(attr[e]));
    }
}

// ---------------- attention: one wave per dst node, batched online softmax ----
// R9-MEASURED VERSION, EXACT SOURCE (100.5us fast-container, VGPR=64, SGPR=80,
// occ 34%). DO NOT REPHRASE THIS LOOP (R7: +8 VGPR -> -9%).
// HARD CONSTRAINT (R5/R6/R7): VGPR <= 64 — TLP-limited at the 8-waves/SIMD max.
// This kernel is the cross-run clock canary: normalize totals by its dur.
__global__ __launch_bounds__(256) void attn_k(
    const uint2* __restrict__ q2, const uint2* __restrict__ kv8u2,
    const float* __restrict__ We,
    __half* __restrict__ hwork, const int2* __restrict__ edat,
    const int* __restrict__ offs,
    double* __restrict__ stats, int n, int nGroups)
{
    int lane = threadIdx.x & 63;
    int wid = threadIdx.x >> 6;
    float4 we = ((const float4*)We)[lane];
    float tsum = 0.f, tsq = 0.f;

    for (int g = blockIdx.x; g < nGroups; g += gridDim.x) {
        int node = g * 4 + wid;
        if (node >= n) continue;
        float4 qv = h4_to_f4(q2[(size_t)node * 256 + lane]);
        float qwe = qv.x * we.x + qv.y * we.y + qv.z * we.z + qv.w * we.w;
        qwe += __shfl_xor(qwe, 1);
        qwe += __shfl_xor(qwe, 2);
        qwe += __shfl_xor(qwe, 4);

        float4 accv = make_float4(0.f, 0.f, 0.f, 0.f);
        float sat = 0.f;
        float m = -INFINITY, l = 0.f;
        int i0 = __builtin_amdgcn_readfirstlane(offs[node]);
        int i1 = __builtin_amdgcn_readfirstlane(offs[node + 1]);

        int abA[8], srA[8], abB[8], srB[8];   // SGPR: attr bits / src index
        uint2 kvA[8], kvB[8];

        auto LOADB = [&](int base, int* ab_, int* sr_, uint2* kv_) {
#pragma unroll
            for (int u = 0; u < 8; u++) {
                int2 ed = edat[base + u];                     // uniform addr
                sr_[u] = __builtin_amdgcn_readfirstlane(ed.x);
                ab_[u] = __builtin_amdgcn_readfirstlane(ed.y);
            }
#pragma unroll
            for (int u = 0; u < 8; u++)
                kv_[u] = (kv8u2 + (size_t)(unsigned)sr_[u] * 64)[lane];
        };

        auto COMPUTE = [&](const int* ab_, const uint2* kv_, int cnt) {
            float pv[8];
#pragma unroll
            for (int u = 0; u < 8; u++) {
                float4 kvf = fp8x4_to_f4(kv_[u].x);
                float p = qv.x * kvf.x + qv.y * kvf.y + qv.z * kvf.z + qv.w * kvf.w;
                p += __shfl_xor(p, 1);
                p += __shfl_xor(p, 2);
                p += __shfl_xor(p, 4);
                p = fmaf(__int_as_float(ab_[u]), qwe, p) * 0.17677669529663687f;
                pv[u] = (u < cnt) ? p : -INFINITY;            // folds away for cnt=8
            }
            float m01 = fmaxf(pv[0], pv[1]), m23 = fmaxf(pv[2], pv[3]);
            float m45 = fmaxf(pv[4], pv[5]), m67 = fmaxf(pv[6], pv[7]);
            float pmax = fmaxf(fmaxf(m01, m23), fmaxf(m45, m67));
            float mn = fmaxf(m, pmax);
            float corr = __expf(m - mn);
            l *= corr;
            sat *= corr;
            accv.x *= corr; accv.y *= corr; accv.z *= corr; accv.w *= corr;
#pragma unroll
            for (int u = 0; u < 8; u++) {
                float wgt = __expf(pv[u] - mn);               // pad: exp(-inf)=0
                l += wgt;
                sat = fmaf(wgt, __int_as_float(ab_[u]), sat);
                float4 vv = fp8x4_to_f4(kv_[u].y);
                accv.x = fmaf(wgt, vv.x, accv.x);
                accv.y = fmaf(wgt, vv.y, accv.y);
                accv.z = fmaf(wgt, vv.z, accv.z);
                accv.w = fmaf(wgt, vv.w, accv.w);
            }
            m = mn;
        };

        if (i0 < i1) {
            int i = i0;
            LOADB(i, abA, srA, kvA);
            while (true) {
                if (i + 8 >= i1) { COMPUTE(abA, kvA, i1 - i); break; }
                LOADB(i + 8, abB, srB, kvB);
                COMPUTE(abA, kvA, 8);
                i += 8;
                if (i + 8 >= i1) { COMPUTE(abB, kvB, i1 - i); break; }
                LOADB(i + 8, abA, srA, kvA);
                COMPUTE(abB, kvB, 8);
                i += 8;
            }
        }

        float inv = (l > 0.f) ? 1.f / l : 0.f;
        float4 sk = h4_to_f4(q2[(size_t)node * 256 + 192 + lane]);
        float sw = sat * inv;
        float4 o;
        o.x = fmaf(accv.x, inv, fmaf(sw, we.x, sk.x));
        o.y = fmaf(accv.y, inv, fmaf(sw, we.y, sk.y));
        o.z = fmaf(accv.z, inv, fmaf(sw, we.z, sk.z));
        o.w = fmaf(accv.w, inv, fmaf(sw, we.w, sk.w));
        store4(hwork + (size_t)node * 256 + lane * 4, o);
        tsum += o.x + o.y + o.z + o.w;
        tsq += o.x * o.x + o.y * o.y + o.z * o.z + o.w * o.w;
    }

#pragma unroll
    for (int d = 1; d < 64; d <<= 1) {
        tsum += __shfl_xor(tsum, d);
        tsq += __shfl_xor(tsq, d);
    }
    __shared__ float red[8];
    if (lane == 0) { red[wid] = tsum; red[4 + wid] = tsq; }
    __syncthreads();
    if (threadIdx.x == 0) {
        double s = (double)red[0] + (double)red[1] + (double)red[2] + (double)red[3];
        double sq = (double)red[4] + (double)red[5] + (double)red[6] + (double)red[7];
        atomicAdd(&stats[0], s);
        atomicAdd(&stats[1], sq);
    }
}

// ---------------- LayerNorm apply (R19: per-block stats, 16B vector IO) ----------------
__global__ __launch_bounds__(256) void ln_apply(
    const uint2* __restrict__ in, __half* __restrict__ out,
    const float4* __restrict__ w4, const float4* __restrict__ b4,
    const double* __restrict__ stats, double cnt, int total4)
{
    __shared__ float sm[2];
    if (threadIdx.x == 0) {
        double mu = stats[0] / cnt;
        double var = stats[1] / cnt - mu * mu;
        if (var < 0.0) var = 0.0;
        sm[0] = (float)mu;
        sm[1] = (float)(1.0 / (sqrt(var) + (double)EPSLN));
    }
    __syncthreads();
    int base = (blockIdx.x * 256 + threadIdx.x) * 4;
    if (base >= total4) return;
    float mean = sm[0];
    float inv = sm[1];

    uint4 ra = *(const uint4*)(in + base);        // i = base, base+1
    uint4 rb = *(const uint4*)(in + base + 2);    // i = base+2, base+3
    uint2 rw[4] = { make_uint2(ra.x, ra.y), make_uint2(ra.z, ra.w),
                    make_uint2(rb.x, rb.y), make_uint2(rb.z, rb.w) };
    uint2 ow[4];
#pragma unroll
    for (int u = 0; u < 4; u++) {
        int i = base + u;
        int c = i & 63;
        float4 xv = h4_to_f4(rw[u]);
        float4 w = w4[c], b = b4[c];
        float4 o;
        o.x = fmaf((xv.x - mean) * inv, w.x, b.x);
        o.y = fmaf((xv.y - mean) * inv, w.y, b.y);
        o.z = fmaf((xv.z - mean) * inv, w.z, b.z);
        o.w = fmaf((xv.w - mean) * inv, w.w, b.w);
        o.x = o.x > 0.f ? o.x : expm1f(o.x);
        o.y = o.y > 0.f ? o.y : expm1f(o.y);
        o.z = o.z > 0.f ? o.z : expm1f(o.z);
        o.w = o.w > 0.f ? o.w : expm1f(o.w);
        union { uint2 u2; __half2 h[2]; } s;
        s.h[0] = __floats2half2_rn(o.x, o.y);
        s.h[1] = __floats2half2_rn(o.z, o.w);
        ow[u] = s.u2;
    }
    uint4 s0 = make_uint4(ow[0].x, ow[0].y, ow[1].x, ow[1].y);
    uint4 s1 = make_uint4(ow[2].x, ow[2].y, ow[3].x, ow[3].y);
    *(uint4*)(out + (size_t)base * 4) = s0;
    *(uint4*)(out + (size_t)(base + 2) * 4) = s1;
}

// ---------------- driver ----------------
extern "C" void kernel_launch(void* const* d_in, const int* in_sizes, int n_in,
                              void* d_out, int out_size, void* d_ws, size_t ws_size,
                              hipStream_t stream)
{
    const float* x      = (const float*)d_in[0];
    const int*   ei     = (const int*)d_in[1];
    const float* eattr  = (const float*)d_in[2];
    const float* Wq1 = (const float*)d_in[3];  const float* bq1 = (const float*)d_in[4];
    const float* Wk1 = (const float*)d_in[5];  const float* bk1 = (const float*)d_in[6];
    const float* Wv1 = (const float*)d_in[7];  const float* bv1 = (const float*)d_in[8];
    const float* We1 = (const float*)d_in[9];
    const float* Ws1 = (const float*)d_in[10]; const float* bs1 = (const float*)d_in[11];
    const float* lnw1 = (const float*)d_in[12]; const float* lnb1 = (const float*)d_in[13];
    const float* Wq2 = (const float*)d_in[14]; const float* bq2 = (const float*)d_in[15];
    const float* Wk2 = (const float*)d_in[16]; const float* bk2 = (const float*)d_in[17];
    const float* Wv2 = (const float*)d_in[18]; const float* bv2 = (const float*)d_in[19];
    const float* We2 = (const float*)d_in[20];
    const float* Ws2 = (const float*)d_in[21]; const float* bs2 = (const float*)d_in[22];
    const float* lnw2 = (const float*)d_in[23]; const float* lnb2 = (const float*)d_in[24];
    const float* Wo  = (const float*)d_in[25]; const float* bo  = (const float*)d_in[26];

    const int N = in_sizes[0] / IN_DIM;
    const int E = in_sizes[2];
    const int* esrc = ei;
    const int* edst = ei + E;

    char* ws = (char*)d_ws;
    size_t off = 0;
    auto alloc = [&](size_t bytes) -> char* {
        char* p = ws + off;
        off += (bytes + 255) / 256 * 256;
        return p;
    };
    int*    counts = (int*)alloc((size_t)N * 4);
    double* stats  = (double*)alloc(64);
    size_t zbytes = off;
    int*    rank   = (int*)alloc((size_t)E * 4);
    int*    offs   = (int*)alloc((size_t)(N + 1) * 4);
    int2*   edat   = (int2*)alloc((size_t)(E + 8) * 8);
    __half* xh     = (__half*)alloc((size_t)N * IN_DIM * 2);
    __half* qkvs   = (__half*)alloc((size_t)N * 1024 * 2);
    unsigned char* kv8 = (unsigned char*)alloc((size_t)N * 512);
    __half* hwork  = (__half*)alloc((size_t)N * HD * 2);
    __half* hio    = (__half*)alloc((size_t)N * HD * 2);
    __half* Wc1    = (__half*)alloc((size_t)1024 * IN_DIM * 2);
    __half* Wc2    = (__half*)alloc((size_t)1024 * HD * 2);
    __half* Wot    = (__half*)alloc((size_t)64 * HD * 2);
    float*  bc1    = (float*)alloc(1024 * 4);
    float*  bc2    = (float*)alloc(1024 * 4);
    int*    part   = (int*)alloc(512);            // scan partials (<=128 blocks)

    hipMemsetAsync(d_ws, 0, zbytes, stream);

    int total4x = N * (IN_DIM / 4);
    int prepWork = total4x > E ? total4x : E;
    if (prepWork < 411648) prepWork = 411648;
    prep_k<<<(prepWork + 255) / 256, 256, 0, stream>>>(
        (const float4*)x, xh, total4x, edst, counts, rank, E,
        Wq1, Wk1, Wv1, Ws1, Wq2, Wk2, Wv2, Ws2, Wo,
        bq1, bk1, bv1, bs1, bq2, bk2, bv2, bs2,
        Wc1, Wc2, Wot, bc1, bc2);

    int nblkS = (N + 511) / 512;                  // 98 for N=50000 (<=128 req'd)
    scan_part_k<<<nblkS, 256, 0, stream>>>(counts, part, N);
    scan_top_k<<<1, 128, 0, stream>>>(part, nblkS);
    scan_fix_k<<<nblkS, 256, 0, stream>>>(counts, part, offs, N);
    scatter_k<<<(E + 255) / 256, 256, 0, stream>>>(esrc, edst, eattr, offs, rank,
                                                   edat, E);

    int nbx = (N + BM - 1) / BM;
    dim3 gqkvs(nbx * 8);                              // 1-D grid for XCD swizzle
    int nGroups = (N + 3) / 4;
    int gaBlocks = nGroups < 2048 ? nGroups : 2048;   // persistent blocks (proven R8 config)
    int total4 = N * (HD / 4);
    dim3 gl((total4 / 4 + 255) / 256);
    dim3 gout((N + 127) / 128);

    // ---- layer 1 ----
    gemm_mfma<<<gqkvs, 256, 0, stream>>>(xh, Wc1, bc1, qkvs, kv8, N, IN_DIM, 1024);
    attn_k<<<gaBlocks, 256, 0, stream>>>((const uint2*)qkvs, (const uint2*)kv8, We1,
                                         hwork, edat, offs, stats, N, nGroups);
    ln_apply<<<gl, 256, 0, stream>>>((const uint2*)hwork, hio,
                                     (const float4*)lnw1, (const float4*)lnb1,
                                     stats, (double)N * HD, total4);

    // ---- layer 2 ----
    gemm_mfma<<<gqkvs, 256, 0, stream>>>(hio, Wc2, bc2, qkvs, kv8, N, HD, 1024);
    attn_k<<<gaBlocks, 256, 0, stream>>>((const uint2*)qkvs, (const uint2*)kv8, We2,
                                         hwork, edat, offs, stats + 2, N, nGroups);
    ln_apply<<<gl, 256, 0, stream>>>((const uint2*)hwork, hio,
                                     (const float4*)lnw2, (const float4*)lnb2,
                                     stats + 2, (double)N * HD, total4);

    // ---- output projection (fp32 out, dedicated 128x64 kernel) ----
    gemm_out_k<<<gout, 256, 0, stream>>>(hio, Wot, bo, (float*)d_out, N);
}

// Round 19
// 497.506 us; speedup vs baseline: 1.0442x; 1.0017x over previous
//
#include <hip/hip_runtime.h>
#include <hip/hip_fp16.h>
#include <math.h>

#define IN_DIM 128
#define HD 256
#define EPSLN 1e-5f

typedef _Float16 half8 __attribute__((ext_vector_type(8)));
typedef float f32x4 __attribute__((ext_vector_type(4)));
typedef float f32x2 __attribute__((ext_vector_type(2)));

// ---------------- helpers ----------------
__device__ inline void store4(float* p, float4 o) { *(float4*)p = o; }
__device__ inline void store4(__half* p, float4 o) {
    union { uint2 u; __half2 h[2]; } s;
    s.h[0] = __floats2half2_rn(o.x, o.y);
    s.h[1] = __floats2half2_rn(o.z, o.w);
    *(uint2*)p = s.u;
}
__device__ inline float4 h4_to_f4(uint2 u) {
    union { unsigned int w; __half2 h; } a, b;
    a.w = u.x; b.w = u.y;
    float2 lo = __half22float2(a.h), hi = __half22float2(b.h);
    return make_float4(lo.x, lo.y, hi.x, hi.y);
}
// 4 floats -> 4 packed fp8 e4m3 (OCP, gfx950 HW cvt)
__device__ inline unsigned int f4_to_fp8x4(float a, float b, float c, float d) {
    int v = 0;
    v = __builtin_amdgcn_cvt_pk_fp8_f32(a, b, v, false);
    v = __builtin_amdgcn_cvt_pk_fp8_f32(c, d, v, true);
    return (unsigned int)v;
}
__device__ inline float4 fp8x4_to_f4(unsigned int u) {
    f32x2 lo = __builtin_amdgcn_cvt_pk_f32_fp8((int)u, false);
    f32x2 hi = __builtin_amdgcn_cvt_pk_f32_fp8((int)u, true);
    return make_float4(lo.x, lo.y, hi.x, hi.y);
}

__device__ inline void async_copy16(const __half* g, _Float16* l) {
    __builtin_amdgcn_global_load_lds(
        (const __attribute__((address_space(1))) void*)g,
        (__attribute__((address_space(3))) void*)l,
        16, 0, 0);
}

// Packed output column mapping: q[0:256) | kv-interleaved[256:768) | skip[768:1024)
__device__ inline void unpermute_col(int n, int& sel, int& c) {
    if (n < 256) { sel = 0; c = n; }
    else if (n < 768) {
        int j = n - 256, chunk = j >> 3, w = j & 7;
        if (w < 4) { sel = 1; c = chunk * 4 + w; }
        else       { sel = 2; c = chunk * 4 + w - 4; }
    } else { sel = 3; c = n - 768; }
}

// ---------------- fused prep: pack x, pack weights/biases, count degrees + ranks ----
// R23: R12-measured-best rank scheme. The returning atomicAdd hidden under
// prep's 411K-thread weight-pack work costs ~nothing; the same atomic as a
// dedicated scatter critical path cost ~20us (R20 lesson, noise-qualified).
__global__ void prep_k(
    const float4* __restrict__ x, __half* __restrict__ xh, int total4,
    const int* __restrict__ dst, int* __restrict__ counts, int* __restrict__ rank, int E,
    const float* __restrict__ Wq1, const float* __restrict__ Wk1,
    const float* __restrict__ Wv1, const float* __restrict__ Ws1,
    const float* __restrict__ Wq2, const float* __restrict__ Wk2,
    const float* __restrict__ Wv2, const float* __restrict__ Ws2,
    const float* __restrict__ Wo,
    const float* __restrict__ bq1, const float* __restrict__ bk1,
    const float* __restrict__ bv1, const float* __restrict__ bs1,
    const float* __restrict__ bq2, const float* __restrict__ bk2,
    const float* __restrict__ bv2, const float* __restrict__ bs2,
    __half* __restrict__ Wc1, __half* __restrict__ Wc2, __half* __restrict__ Wot,
    float* __restrict__ bc1, float* __restrict__ bc2)
{
    int idx = blockIdx.x * 256 + threadIdx.x;
    if (idx < total4) store4(xh + (size_t)idx * 4, x[idx]);
    if (idx < E) rank[idx] = atomicAdd(&counts[dst[idx]], 1);   // rank within dst bucket
    if (idx < 131072) {
        int n = idx >> 7, k = idx & 127;
        int sel, c; unpermute_col(n, sel, c);
        const float* W = (sel == 0) ? Wq1 : (sel == 1) ? Wk1 : (sel == 2) ? Wv1 : Ws1;
        Wc1[idx] = __float2half(W[(size_t)k * 256 + c]);
    } else if (idx < 393216) {
        int j = idx - 131072;
        int n = j >> 8, k = j & 255;
        int sel, c; unpermute_col(n, sel, c);
        const float* W = (sel == 0) ? Wq2 : (sel == 1) ? Wk2 : (sel == 2) ? Wv2 : Ws2;
        Wc2[j] = __float2half(W[(size_t)k * 256 + c]);
    } else if (idx < 409600) {
        int j = idx - 393216;
        int n = j >> 8, k = j & 255;
        Wot[j] = __float2half(Wo[(size_t)k * 64 + n]);
    } else if (idx < 410624) {
        int n = idx - 409600;
        int sel, c; unpermute_col(n, sel, c);
        const float* b = (sel == 0) ? bq1 : (sel == 1) ? bk1 : (sel == 2) ? bv1 : bs1;
        bc1[n] = b[c];
    } else if (idx < 411648) {
        int n = idx - 410624;
        int sel, c; unpermute_col(n, sel, c);
        const float* b = (sel == 0) ? bq2 : (sel == 1) ? bk2 : (sel == 2) ? bv2 : bs2;
        bc2[n] = b[c];
    }
}

// ---------------- MFMA GEMM: C[M x Nc] = A[M x K] @ Wt^T + bias (f16 out) ----------------
// R13: 1-D grid + XCD-grouping swizzle (measured R4: ~44us win across both gemms).
// R17/R18: BK=32 single-barrier double-buffer (measured R11: neutral; kept as
// the verified config). LDS: As0@0, Bs0@8K, As1@16K, Bs1@24K within the
// 34,816B epilogue region. Buffer bases computed per-use (LDS pointer arrays
// fail to compile on gfx950 — R10 lesson).
#define BM 128
#define BN 128
#define TROWB 272   // f16 out-tile row stride (bytes)

__global__ __launch_bounds__(256) void gemm_mfma(
    const __half* __restrict__ A, const __half* __restrict__ Wt,
    const float* __restrict__ bias, __half* __restrict__ C,
    unsigned char* __restrict__ kv8,
    int M, int K, int Nc)
{
    __shared__ char smem[BM * TROWB];          // 34,816 B; dbuf overlaid below

    int tid = threadIdx.x;
    int lane = tid & 63, w = tid >> 6;
    int wm = w >> 1, wn = w & 1;
    int quad = lane >> 4, l16 = lane & 15;
    // XCD swizzle: nwg = nbx*8 (exact multiple of 8 XCDs)
    int nbx = (int)gridDim.x >> 3;
    int wkr = ((int)blockIdx.x & 7) * nbx + ((int)blockIdx.x >> 3);
    int row0 = (wkr >> 3) * BM;
    int col0 = (wkr & 7) * BN;

    f32x4 acc[4][4];
#pragma unroll
    for (int i = 0; i < 4; i++)
#pragma unroll
        for (int j = 0; j < 4; j++) acc[i][j] = (f32x4){0.f, 0.f, 0.f, 0.f};

    int srow = lane >> 2;      // 0..15 (16 rows per wave-instruction at BK=32)
    int schunk = lane & 3;     // 4 chunks of 8 f16 per 64B row

    int nt = K >> 5;           // K/32 steps

    // STAGE(step, buf): issue A+B tile loads for k0 = step*32 into buffer buf
    auto STAGE = [&](int step, int buf) {
        int k0 = step << 5;
        _Float16* Asb = (_Float16*)(smem + buf * 16384);
        _Float16* Bsb = (_Float16*)(smem + 8192 + buf * 16384);
#pragma unroll
        for (int t = 0; t < 2; t++) {
            int r = w * 32 + t * 16 + srow;
            int gr = row0 + r; if (gr > M - 1) gr = M - 1;
            int gchunk = schunk ^ ((r ^ (r >> 2)) & 3);
            async_copy16(&A[(size_t)gr * K + k0 + gchunk * 8], &Asb[(w * 32 + t * 16) * 32]);
        }
#pragma unroll
        for (int t = 0; t < 2; t++) {
            int r = w * 32 + t * 16 + srow;
            int gc = col0 + r; if (gc > Nc - 1) gc = Nc - 1;
            int gchunk = schunk ^ ((r ^ (r >> 2)) & 3);
            async_copy16(&Wt[(size_t)gc * K + k0 + gchunk * 8], &Bsb[(w * 32 + t * 16) * 32]);
        }
    };

    STAGE(0, 0);
    __syncthreads();

    for (int t = 0; t < nt; ++t) {
        if (t + 1 < nt) STAGE(t + 1, (t + 1) & 1);
        _Float16* Asb = (_Float16*)(smem + (t & 1) * 16384);
        _Float16* Bsb = (_Float16*)(smem + 8192 + (t & 1) * 16384);
        half8 af[4], bf[4];
#pragma unroll
        for (int i = 0; i < 4; i++) {
            int ra = wm * 64 + i * 16 + l16;
            af[i] = *(half8*)&Asb[ra * 32 + ((quad ^ ((ra ^ (ra >> 2)) & 3)) * 8)];
            int rb = wn * 64 + i * 16 + l16;
            bf[i] = *(half8*)&Bsb[rb * 32 + ((quad ^ ((rb ^ (rb >> 2)) & 3)) * 8)];
        }
#pragma unroll
        for (int i = 0; i < 4; i++)
#pragma unroll
            for (int j = 0; j < 4; j++)
                acc[i][j] = __builtin_amdgcn_mfma_f32_16x16x32_f16(af[i], bf[j], acc[i][j], 0, 0, 0);
        __syncthreads();
    }

#pragma unroll
    for (int j = 0; j < 4; j++) {
        int tcol = wn * 64 + j * 16 + l16;
        float bb = (col0 + tcol < Nc) ? bias[col0 + tcol] : 0.f;
#pragma unroll
        for (int i = 0; i < 4; i++) {
#pragma unroll
            for (int r = 0; r < 4; r++) {
                int trow = wm * 64 + i * 16 + quad * 4 + r;
                ((__half*)(smem + trow * TROWB))[tcol] = __float2half(acc[i][j][r] + bb);
            }
        }
    }
    __syncthreads();
    bool iskv = (col0 >= 256) && (col0 < 768);
    int crow = tid >> 4, cchunk = tid & 15;
    for (int p = 0; p < 8; p++) {
        int trow = p * 16 + crow;
        int grow = row0 + trow;
        if (grow >= M) continue;
        uint4 val = *(uint4*)(smem + trow * TROWB + cchunk * 16);
        if (iskv) {
            float4 lo = h4_to_f4(make_uint2(val.x, val.y));
            float4 hi = h4_to_f4(make_uint2(val.z, val.w));
            uint2 o8;
            o8.x = f4_to_fp8x4(lo.x, lo.y, lo.z, lo.w);
            o8.y = f4_to_fp8x4(hi.x, hi.y, hi.z, hi.w);
            *(uint2*)&kv8[(size_t)grow * 512 + (col0 - 256) + cchunk * 8] = o8;
        } else {
            *(uint4*)&C[(size_t)grow * Nc + col0 + cchunk * 8] = val;
        }
    }
}

// ---------------- output GEMM: D[M x 64] = A[M x 256] @ Wot^T + bo (fp32 out) ----------
// R17/R18: BK=32 single-barrier double-buffer. LDS 24KB.
// Layout (halfs): As0@0 (4096), As1@4096, Bs0@8192 (2048), Bs1@10240.
__global__ __launch_bounds__(256) void gemm_out_k(
    const __half* __restrict__ A, const __half* __restrict__ Wot,
    const float* __restrict__ bias, float* __restrict__ D, int M)
{
    __shared__ _Float16 smem[12288];   // 24 KB
    int tid = threadIdx.x;
    int lane = tid & 63, w = tid >> 6;
    int quad = lane >> 4, l16 = lane & 15;
    int row0 = blockIdx.x * 128;
    const int K = 256;

    f32x4 acc[2][4];
#pragma unroll
    for (int i = 0; i < 2; i++)
#pragma unroll
        for (int j = 0; j < 4; j++) acc[i][j] = (f32x4){0.f, 0.f, 0.f, 0.f};

    int srow = lane >> 2;
    int schunk = lane & 3;
    const int nt = 8;   // 256/32

    auto STAGE = [&](int step, int buf) {
        int k0 = step << 5;
        _Float16* Asb = smem + buf * 4096;
        _Float16* Bsb = smem + 8192 + buf * 2048;
#pragma unroll
        for (int t = 0; t < 2; t++) {
            int r = w * 32 + t * 16 + srow;
            int gr = row0 + r; if (gr > M - 1) gr = M - 1;
            int gchunk = schunk ^ ((r ^ (r >> 2)) & 3);
            async_copy16(&A[(size_t)gr * K + k0 + gchunk * 8], &Asb[(w * 32 + t * 16) * 32]);
        }
        {
            int r = w * 16 + srow;       // 64 weight rows, one wave-inst per wave
            int gchunk = schunk ^ ((r ^ (r >> 2)) & 3);
            async_copy16(&Wot[(size_t)r * K + k0 + gchunk * 8], &Bsb[(w * 16) * 32]);
        }
    };

    STAGE(0, 0);
    __syncthreads();

    for (int t = 0; t < nt; ++t) {
        if (t + 1 < nt) STAGE(t + 1, (t + 1) & 1);
        _Float16* Asb = smem + (t & 1) * 4096;
        _Float16* Bsb = smem + 8192 + (t & 1) * 2048;
        half8 af[2], bf[4];
#pragma unroll
        for (int i = 0; i < 2; i++) {
            int ra = w * 32 + i * 16 + l16;
            af[i] = *(half8*)&Asb[ra * 32 + ((quad ^ ((ra ^ (ra >> 2)) & 3)) * 8)];
        }
#pragma unroll
        for (int j = 0; j < 4; j++) {
            int rb = j * 16 + l16;
            bf[j] = *(half8*)&Bsb[rb * 32 + ((quad ^ ((rb ^ (rb >> 2)) & 3)) * 8)];
        }
#pragma unroll
        for (int i = 0; i < 2; i++)
#pragma unroll
            for (int j = 0; j < 4; j++)
                acc[i][j] = __builtin_amdgcn_mfma_f32_16x16x32_f16(af[i], bf[j], acc[i][j], 0, 0, 0);
        __syncthreads();
    }

#pragma unroll
    for (int i = 0; i < 2; i++) {
#pragma unroll
        for (int j = 0; j < 4; j++) {
            int gcol = j * 16 + l16;
            float bb = bias[gcol];
#pragma unroll
            for (int r = 0; r < 4; r++) {
                int grow = row0 + w * 32 + i * 16 + quad * 4 + r;
                if (grow < M) D[(size_t)grow * 64 + gcol] = acc[i][j][r] + bb;
            }
        }
    }
}

// ---------------- edge bucketing: 3-phase parallel scan (R19, measured -87us) ----------
__global__ __launch_bounds__(256) void scan_part_k(const int* __restrict__ counts,
                                                   int* __restrict__ part, int n)
{
    int b = blockIdx.x, t = threadIdx.x;
    int i0 = b * 512 + t * 2;
    int s = 0;
    if (i0 < n) s += counts[i0];
    if (i0 + 1 < n) s += counts[i0 + 1];
    int lane = t & 63, wid = t >> 6;
    int v = s;
#pragma unroll
    for (int d = 1; d < 64; d <<= 1) v += __shfl_xor(v, d);
    __shared__ int ws[4];
    if (lane == 0) ws[wid] = v;
    __syncthreads();
    if (t == 0) part[b] = ws[0] + ws[1] + ws[2] + ws[3];
}

__global__ __launch_bounds__(128) void scan_top_k(int* __restrict__ part, int nb)
{
    // exclusive prefix over nb (<=128) entries, in place
    int t = threadIdx.x, lane = t & 63, wid = t >> 6;
    int orig = (t < nb) ? part[t] : 0;
    int v = orig;
#pragma unroll
    for (int d = 1; d < 64; d <<= 1) {
        int u = __shfl_up(v, (unsigned)d, 64);
        if (lane >= d) v += u;
    }
    __shared__ int wsum[2];
    if (lane == 63) wsum[wid] = v;
    __syncthreads();
    int add = (wid == 1) ? wsum[0] : 0;
    if (t < nb) part[t] = v + add - orig;   // exclusive base
}

__global__ __launch_bounds__(256) void scan_fix_k(const int* __restrict__ counts,
                                                  const int* __restrict__ part,
                                                  int* __restrict__ offs, int n)
{
    int b = blockIdx.x, t = threadIdx.x;
    int lane = t & 63, wid = t >> 6;
    int i0 = b * 512 + t * 2;
    int c0 = (i0 < n) ? counts[i0] : 0;
    int c1 = (i0 + 1 < n) ? counts[i0 + 1] : 0;
    int s = c0 + c1;
    int v = s;
#pragma unroll
    for (int d = 1; d < 64; d <<= 1) {
        int u = __shfl_up(v, (unsigned)d, 64);
        if (lane >= d) v += u;
    }
    __shared__ int wsum[4], wpre[4];
    if (lane == 63) wsum[wid] = v;
    __syncthreads();
    if (t == 0) { int a = 0; for (int i = 0; i < 4; i++) { wpre[i] = a; a += wsum[i]; } }
    __syncthreads();
    int pre = part[b] + wpre[wid] + v - s;   // exclusive prefix for this thread
    if (i0 < n) offs[i0] = pre;
    if (i0 + 1 < n) offs[i0 + 1] = pre + c0;
    int end = i0 + 2; if (end > n) end = n;
    if (end == n) offs[n] = pre + c0 + c1;   // racing writers all write the total
}

// atomic-free: position = segment offset + precomputed rank (R12-measured best).
// Pads 8 entries past the end so attn tail batches can overrun safely.
__global__ void scatter_k(const int* __restrict__ src, const int* __restrict__ dst,
                          const float* __restrict__ attr, const int* __restrict__ offs,
                          const int* __restrict__ rank, int2* __restrict__ edat, int E)
{
    int e = blockIdx.x * 256 + threadIdx.x;
    if (e < 8) edat[E + e] = make_int2(0, 0);
    if (e < E) {
        int p = offs[dst[e]] + rank[e];
        edat[p] = make_int2(src[e], __float_as_int(attr[e]));
    }
}

// ---------------- attention: one wave per dst node, batched online softmax ----
// R9-MEASURED VERSION, EXACT SOURCE (100.5us fast-container, VGPR=64, SGPR=80,
// occ 34%). DO NOT REPHRASE THIS LOOP (R7: +8 VGPR -> -9%).
// HARD CONSTRAINT (R5/R6/R7): VGPR <= 64 — TLP-limited at the 8-waves/SIMD max.
// This kernel is the cross-run clock canary: normalize totals by its dur.
__global__ __launch_bounds__(256) void attn_k(
    const uint2* __restrict__ q2, const uint2* __restrict__ kv8u2,
    const float* __restrict__ We,
    __half* __restrict__ hwork, const int2* __restrict__ edat,
    const int* __restrict__ offs,
    double* __restrict__ stats, int n, int nGroups)
{
    int lane = threadIdx.x & 63;
    int wid = threadIdx.x >> 6;
    float4 we = ((const float4*)We)[lane];
    float tsum = 0.f, tsq = 0.f;

    for (int g = blockIdx.x; g < nGroups; g += gridDim.x) {
        int node = g * 4 + wid;
        if (node >= n) continue;
        float4 qv = h4_to_f4(q2[(size_t)node * 256 + lane]);
        float qwe = qv.x * we.x + qv.y * we.y + qv.z * we.z + qv.w * we.w;
        qwe += __shfl_xor(qwe, 1);
        qwe += __shfl_xor(qwe, 2);
        qwe += __shfl_xor(qwe, 4);

        float4 accv = make_float4(0.f, 0.f, 0.f, 0.f);
        float sat = 0.f;
        float m = -INFINITY, l = 0.f;
        int i0 = __builtin_amdgcn_readfirstlane(offs[node]);
        int i1 = __builtin_amdgcn_readfirstlane(offs[node + 1]);

        int abA[8], srA[8], abB[8], srB[8];   // SGPR: attr bits / src index
        uint2 kvA[8], kvB[8];

        auto LOADB = [&](int base, int* ab_, int* sr_, uint2* kv_) {
#pragma unroll
            for (int u = 0; u < 8; u++) {
                int2 ed = edat[base + u];                     // uniform addr
                sr_[u] = __builtin_amdgcn_readfirstlane(ed.x);
                ab_[u] = __builtin_amdgcn_readfirstlane(ed.y);
            }
#pragma unroll
            for (int u = 0; u < 8; u++)
                kv_[u] = (kv8u2 + (size_t)(unsigned)sr_[u] * 64)[lane];
        };

        auto COMPUTE = [&](const int* ab_, const uint2* kv_, int cnt) {
            float pv[8];
#pragma unroll
            for (int u = 0; u < 8; u++) {
                float4 kvf = fp8x4_to_f4(kv_[u].x);
                float p = qv.x * kvf.x + qv.y * kvf.y + qv.z * kvf.z + qv.w * kvf.w;
                p += __shfl_xor(p, 1);
                p += __shfl_xor(p, 2);
                p += __shfl_xor(p, 4);
                p = fmaf(__int_as_float(ab_[u]), qwe, p) * 0.17677669529663687f;
                pv[u] = (u < cnt) ? p : -INFINITY;            // folds away for cnt=8
            }
            float m01 = fmaxf(pv[0], pv[1]), m23 = fmaxf(pv[2], pv[3]);
            float m45 = fmaxf(pv[4], pv[5]), m67 = fmaxf(pv[6], pv[7]);
            float pmax = fmaxf(fmaxf(m01, m23), fmaxf(m45, m67));
            float mn = fmaxf(m, pmax);
            float corr = __expf(m - mn);
            l *= corr;
            sat *= corr;
            accv.x *= corr; accv.y *= corr; accv.z *= corr; accv.w *= corr;
#pragma unroll
            for (int u = 0; u < 8; u++) {
                float wgt = __expf(pv[u] - mn);               // pad: exp(-inf)=0
                l += wgt;
                sat = fmaf(wgt, __int_as_float(ab_[u]), sat);
                float4 vv = fp8x4_to_f4(kv_[u].y);
                accv.x = fmaf(wgt, vv.x, accv.x);
                accv.y = fmaf(wgt, vv.y, accv.y);
                accv.z = fmaf(wgt, vv.z, accv.z);
                accv.w = fmaf(wgt, vv.w, accv.w);
            }
            m = mn;
        };

        if (i0 < i1) {
            int i = i0;
            LOADB(i, abA, srA, kvA);
            while (true) {
                if (i + 8 >= i1) { COMPUTE(abA, kvA, i1 - i); break; }
                LOADB(i + 8, abB, srB, kvB);
                COMPUTE(abA, kvA, 8);
                i += 8;
                if (i + 8 >= i1) { COMPUTE(abB, kvB, i1 - i); break; }
                LOADB(i + 8, abA, srA, kvA);
                COMPUTE(abB, kvB, 8);
                i += 8;
            }
        }

        float inv = (l > 0.f) ? 1.f / l : 0.f;
        float4 sk = h4_to_f4(q2[(size_t)node * 256 + 192 + lane]);
        float sw = sat * inv;
        float4 o;
        o.x = fmaf(accv.x, inv, fmaf(sw, we.x, sk.x));
        o.y = fmaf(accv.y, inv, fmaf(sw, we.y, sk.y));
        o.z = fmaf(accv.z, inv, fmaf(sw, we.z, sk.z));
        o.w = fmaf(accv.w, inv, fmaf(sw, we.w, sk.w));
        store4(hwork + (size_t)node * 256 + lane * 4, o);
        tsum += o.x + o.y + o.z + o.w;
        tsq += o.x * o.x + o.y * o.y + o.z * o.z + o.w * o.w;
    }

#pragma unroll
    for (int d = 1; d < 64; d <<= 1) {
        tsum += __shfl_xor(tsum, d);
        tsq += __shfl_xor(tsq, d);
    }
    __shared__ float red[8];
    if (lane == 0) { red[wid] = tsum; red[4 + wid] = tsq; }
    __syncthreads();
    if (threadIdx.x == 0) {
        double s = (double)red[0] + (double)red[1] + (double)red[2] + (double)red[3];
        double sq = (double)red[4] + (double)red[5] + (double)red[6] + (double)red[7];
        atomicAdd(&stats[0], s);
        atomicAdd(&stats[1], sq);
    }
}

// ---------------- LayerNorm apply (R19: per-block stats, 16B vector IO) ----------------
__global__ __launch_bounds__(256) void ln_apply(
    const uint2* __restrict__ in, __half* __restrict__ out,
    const float4* __restrict__ w4, const float4* __restrict__ b4,
    const double* __restrict__ stats, double cnt, int total4)
{
    __shared__ float sm[2];
    if (threadIdx.x == 0) {
        double mu = stats[0] / cnt;
        double var = stats[1] / cnt - mu * mu;
        if (var < 0.0) var = 0.0;
        sm[0] = (float)mu;
        sm[1] = (float)(1.0 / (sqrt(var) + (double)EPSLN));
    }
    __syncthreads();
    int base = (blockIdx.x * 256 + threadIdx.x) * 4;
    if (base >= total4) return;
    float mean = sm[0];
    float inv = sm[1];

    uint4 ra = *(const uint4*)(in + base);        // i = base, base+1
    uint4 rb = *(const uint4*)(in + base + 2);    // i = base+2, base+3
    uint2 rw[4] = { make_uint2(ra.x, ra.y), make_uint2(ra.z, ra.w),
                    make_uint2(rb.x, rb.y), make_uint2(rb.z, rb.w) };
    uint2 ow[4];
#pragma unroll
    for (int u = 0; u < 4; u++) {
        int i = base + u;
        int c = i & 63;
        float4 xv = h4_to_f4(rw[u]);
        float4 w = w4[c], b = b4[c];
        float4 o;
        o.x = fmaf((xv.x - mean) * inv, w.x, b.x);
        o.y = fmaf((xv.y - mean) * inv, w.y, b.y);
        o.z = fmaf((xv.z - mean) * inv, w.z, b.z);
        o.w = fmaf((xv.w - mean) * inv, w.w, b.w);
        o.x = o.x > 0.f ? o.x : expm1f(o.x);
        o.y = o.y > 0.f ? o.y : expm1f(o.y);
        o.z = o.z > 0.f ? o.z : expm1f(o.z);
        o.w = o.w > 0.f ? o.w : expm1f(o.w);
        union { uint2 u2; __half2 h[2]; } s;
        s.h[0] = __floats2half2_rn(o.x, o.y);
        s.h[1] = __floats2half2_rn(o.z, o.w);
        ow[u] = s.u2;
    }
    uint4 s0 = make_uint4(ow[0].x, ow[0].y, ow[1].x, ow[1].y);
    uint4 s1 = make_uint4(ow[2].x, ow[2].y, ow[3].x, ow[3].y);
    *(uint4*)(out + (size_t)base * 4) = s0;
    *(uint4*)(out + (size_t)(base + 2) * 4) = s1;
}

// ---------------- driver ----------------
extern "C" void kernel_launch(void* const* d_in, const int* in_sizes, int n_in,
                              void* d_out, int out_size, void* d_ws, size_t ws_size,
                              hipStream_t stream)
{
    const float* x      = (const float*)d_in[0];
    const int*   ei     = (const int*)d_in[1];
    const float* eattr  = (const float*)d_in[2];
    const float* Wq1 = (const float*)d_in[3];  const float* bq1 = (const float*)d_in[4];
    const float* Wk1 = (const float*)d_in[5];  const float* bk1 = (const float*)d_in[6];
    const float* Wv1 = (const float*)d_in[7];  const float* bv1 = (const float*)d_in[8];
    const float* We1 = (const float*)d_in[9];
    const float* Ws1 = (const float*)d_in[10]; const float* bs1 = (const float*)d_in[11];
    const float* lnw1 = (const float*)d_in[12]; const float* lnb1 = (const float*)d_in[13];
    const float* Wq2 = (const float*)d_in[14]; const float* bq2 = (const float*)d_in[15];
    const float* Wk2 = (const float*)d_in[16]; const float* bk2 = (const float*)d_in[17];
    const float* Wv2 = (const float*)d_in[18]; const float* bv2 = (const float*)d_in[19];
    const float* We2 = (const float*)d_in[20];
    const float* Ws2 = (const float*)d_in[21]; const float* bs2 = (const float*)d_in[22];
    const float* lnw2 = (const float*)d_in[23]; const float* lnb2 = (const float*)d_in[24];
    const float* Wo  = (const float*)d_in[25]; const float* bo  = (const float*)d_in[26];

    const int N = in_sizes[0] / IN_DIM;
    const int E = in_sizes[2];
    const int* esrc = ei;
    const int* edst = ei + E;

    char* ws = (char*)d_ws;
    size_t off = 0;
    auto alloc = [&](size_t bytes) -> char* {
        char* p = ws + off;
        off += (bytes + 255) / 256 * 256;
        return p;
    };
    int*    counts = (int*)alloc((size_t)N * 4);
    double* stats  = (double*)alloc(64);
    size_t zbytes = off;
    int*    rank   = (int*)alloc((size_t)E * 4);
    int*    offs   = (int*)alloc((size_t)(N + 1) * 4);
    int2*   edat   = (int2*)alloc((size_t)(E + 8) * 8);
    __half* xh     = (__half*)alloc((size_t)N * IN_DIM * 2);
    __half* qkvs   = (__half*)alloc((size_t)N * 1024 * 2);
    unsigned char* kv8 = (unsigned char*)alloc((size_t)N * 512);
    __half* hwork  = (__half*)alloc((size_t)N * HD * 2);
    __half* hio    = (__half*)alloc((size_t)N * HD * 2);
    __half* Wc1    = (__half*)alloc((size_t)1024 * IN_DIM * 2);
    __half* Wc2    = (__half*)alloc((size_t)1024 * HD * 2);
    __half* Wot    = (__half*)alloc((size_t)64 * HD * 2);
    float*  bc1    = (float*)alloc(1024 * 4);
    float*  bc2    = (float*)alloc(1024 * 4);
    int*    part   = (int*)alloc(512);            // scan partials (<=128 blocks)

    hipMemsetAsync(d_ws, 0, zbytes, stream);

    int total4x = N * (IN_DIM / 4);
    int prepWork = total4x > E ? total4x : E;
    if (prepWork < 411648) prepWork = 411648;
    prep_k<<<(prepWork + 255) / 256, 256, 0, stream>>>(
        (const float4*)x, xh, total4x, edst, counts, rank, E,
        Wq1, Wk1, Wv1, Ws1, Wq2, Wk2, Wv2, Ws2, Wo,
        bq1, bk1, bv1, bs1, bq2, bk2, bv2, bs2,
        Wc1, Wc2, Wot, bc1, bc2);

    int nblkS = (N + 511) / 512;                  // 98 for N=50000 (<=128 req'd)
    scan_part_k<<<nblkS, 256, 0, stream>>>(counts, part, N);
    scan_top_k<<<1, 128, 0, stream>>>(part, nblkS);
    scan_fix_k<<<nblkS, 256, 0, stream>>>(counts, part, offs, N);
    scatter_k<<<(E + 255) / 256, 256, 0, stream>>>(esrc, edst, eattr, offs, rank,
                                                   edat, E);

    int nbx = (N + BM - 1) / BM;
    dim3 gqkvs(nbx * 8);                              // 1-D grid for XCD swizzle
    int nGroups = (N + 3) / 4;
    int gaBlocks = nGroups < 2048 ? nGroups : 2048;   // persistent blocks (proven R8 config)
    int total4 = N * (HD / 4);
    dim3 gl((total4 / 4 + 255) / 256);
    dim3 gout((N + 127) / 128);

    // ---- layer 1 ----
    gemm_mfma<<<gqkvs, 256, 0, stream>>>(xh, Wc1, bc1, qkvs, kv8, N, IN_DIM, 1024);
    attn_k<<<gaBlocks, 256, 0, stream>>>((const uint2*)qkvs, (const uint2*)kv8, We1,
                                         hwork, edat, offs, stats, N, nGroups);
    ln_apply<<<gl, 256, 0, stream>>>((const uint2*)hwork, hio,
                                     (const float4*)lnw1, (const float4*)lnb1,
                                     stats, (double)N * HD, total4);

    // ---- layer 2 ----
    gemm_mfma<<<gqkvs, 256, 0, stream>>>(hio, Wc2, bc2, qkvs, kv8, N, HD, 1024);
    attn_k<<<gaBlocks, 256, 0, stream>>>((const uint2*)qkvs, (const uint2*)kv8, We2,
                                         hwork, edat, offs, stats + 2, N, nGroups);
    ln_apply<<<gl, 256, 0, stream>>>((const uint2*)hwork, hio,
                                     (const float4*)lnw2, (const float4*)lnb2,
                                     stats + 2, (double)N * HD, total4);

    // ---- output projection (fp32 out, dedicated 128x64 kernel) ----
    gemm_out_k<<<gout, 256, 0, stream>>>(hio, Wot, bo, (float*)d_out, N);
}